// Round 5
// baseline (323.254 us; speedup 1.0000x reference)
//
#include <hip/hip_runtime.h>
#include <cstddef>

#define SS 1024
#define DF 768
#define NBATCH 16
#define GAT_ALPHA 0.2f

typedef _Float16 f16x8 __attribute__((ext_vector_type(8)));
typedef _Float16 f16x4 __attribute__((ext_vector_type(4)));
typedef float f32x4 __attribute__((ext_vector_type(4)));

// async global->LDS, 16B per lane. LDS dest is wave-uniform base + lane*16.
__device__ __forceinline__ void gload16(const void* g, void* l) {
  __builtin_amdgcn_global_load_lds(
      (const __attribute__((address_space(1))) void*)g,
      (__attribute__((address_space(3))) void*)l, 16, 0, 0);
}

__device__ __forceinline__ float lrelu(float t) {
  return fmaxf(t, GAT_ALPHA * t);
}

// ---------------------------------------------------------------------------
// fp32 -> fp16 convert, 4 elems/thread
// ---------------------------------------------------------------------------
__global__ __launch_bounds__(256) void f32tof16_k(const float* __restrict__ in,
                                                  _Float16* __restrict__ out,
                                                  int n) {
  int idx = (blockIdx.x * 256 + threadIdx.x) * 4;
  if (idx + 3 < n) {
    float4 v = *(const float4*)&in[idx];
    f16x4 o;
    o[0] = (_Float16)v.x;
    o[1] = (_Float16)v.y;
    o[2] = (_Float16)v.z;
    o[3] = (_Float16)v.w;
    *(f16x4*)&out[idx] = o;
  }
}

// ---------------------------------------------------------------------------
// pack: int32 mask (64MB) -> bitmask (2MB). byte t holds j=8t..8t+7 (bit k).
// ---------------------------------------------------------------------------
__global__ __launch_bounds__(256) void pack_k(const int* __restrict__ mask,
                                              unsigned char* __restrict__ bm) {
  const size_t t = (size_t)blockIdx.x * 256 + threadIdx.x;  // byte idx, 2M
  const int* mp = mask + t * 8;
  const int4 a = *(const int4*)mp;
  const int4 c = *(const int4*)(mp + 4);
  unsigned v = (unsigned)(a.x > 0) | ((unsigned)(a.y > 0) << 1) |
               ((unsigned)(a.z > 0) << 2) | ((unsigned)(a.w > 0) << 3) |
               ((unsigned)(c.x > 0) << 4) | ((unsigned)(c.y > 0) << 5) |
               ((unsigned)(c.z > 0) << 6) | ((unsigned)(c.w > 0) << 7);
  bm[t] = (unsigned char)v;
}

// ---------------------------------------------------------------------------
// GEMM1: hT16[b][n][s] = f16( sum_k X16[m,k]*W16[n,k] + Wb[n] ),  m=b*1024+s
// 128x128 tile, BK=32, 4 waves (2x2), 4x4 16x16x32 f16 MFMA frags per wave.
// ---------------------------------------------------------------------------
__global__ __launch_bounds__(256) void gemm1_k(
    const _Float16* __restrict__ X16, const _Float16* __restrict__ W16,
    const float* __restrict__ Wbl, _Float16* __restrict__ hT16) {
  __shared__ _Float16 sA[128 * 32];
  __shared__ _Float16 sB[128 * 32];
  const int m0 = blockIdx.x * 128;
  const int n0 = blockIdx.y * 128;
  const int t = threadIdx.x;
  const int w = t >> 6, lane = t & 63;
  const int wr = w >> 1, wc = w & 1;

  f32x4 acc[4][4];
#pragma unroll
  for (int mi = 0; mi < 4; ++mi)
#pragma unroll
    for (int ni = 0; ni < 4; ++ni) acc[mi][ni] = (f32x4)(0.f);

  const int srow = w * 32 + (lane >> 2);
  const int scol = (lane & 3) * 8;

  for (int k0 = 0; k0 < DF; k0 += 32) {
#pragma unroll
    for (int q = 0; q < 2; ++q) {
      int row = srow + q * 16;
      gload16(&X16[(size_t)(m0 + row) * DF + k0 + scol],
              (char*)sA + w * 2048 + q * 1024);
      gload16(&W16[(size_t)(n0 + row) * DF + k0 + scol],
              (char*)sB + w * 2048 + q * 1024);
    }
    __syncthreads();
    f16x8 af[4], bf[4];
#pragma unroll
    for (int mi = 0; mi < 4; ++mi)
      af[mi] = *(const f16x8*)&sA[(wr * 64 + mi * 16 + (lane & 15)) * 32 +
                                  (lane >> 4) * 8];
#pragma unroll
    for (int ni = 0; ni < 4; ++ni)
      bf[ni] = *(const f16x8*)&sB[(wc * 64 + ni * 16 + (lane & 15)) * 32 +
                                  (lane >> 4) * 8];
#pragma unroll
    for (int mi = 0; mi < 4; ++mi)
#pragma unroll
      for (int ni = 0; ni < 4; ++ni)
        acc[mi][ni] = __builtin_amdgcn_mfma_f32_16x16x32_f16(
            af[mi], bf[ni], acc[mi][ni], 0, 0, 0);
    __syncthreads();
  }

  const int cg = lane >> 4, cr = lane & 15;
#pragma unroll
  for (int mi = 0; mi < 4; ++mi) {
#pragma unroll
    for (int ni = 0; ni < 4; ++ni) {
      const int col = n0 + wc * 64 + ni * 16 + cr;
      const float bias = Wbl[col];
      const int row0 = m0 + wr * 64 + mi * 16 + cg * 4;
      f16x4 tv;
#pragma unroll
      for (int r = 0; r < 4; ++r) tv[r] = (_Float16)(acc[mi][ni][r] + bias);
      const int bb = row0 >> 10, s0 = row0 & 1023;
      *(f16x4*)&hT16[((size_t)bb * DF + col) * SS + s0] = tv;
    }
  }
}

// ---------------------------------------------------------------------------
// rowdots2: si/sj partials from hT16 (coalesced: thread owns 4 consecutive s,
// loops d within its chunk). psi/psj[dc][b*1024+s], combined by rowcomb.
// ---------------------------------------------------------------------------
__global__ __launch_bounds__(256) void rowdots2_k(
    const _Float16* __restrict__ hT, const float* __restrict__ Al,
    float* __restrict__ psi, float* __restrict__ psj) {
  const int dc = blockIdx.x;  // 0..15 (48 d's each)
  const int b = blockIdx.y;   // 0..15
  const int t = threadIdx.x;
  const int s4 = t * 4;
  __shared__ float sa[48], sd[48];
  if (t < 48) {
    sa[t] = Al[dc * 48 + t];
    sd[t] = Al[DF + dc * 48 + t];
  }
  __syncthreads();
  float as[4] = {0.f, 0.f, 0.f, 0.f}, ad[4] = {0.f, 0.f, 0.f, 0.f};
  const _Float16* hp = hT + ((size_t)b * DF + dc * 48) * SS + s4;
#pragma unroll 4
  for (int q = 0; q < 48; ++q) {
    const f16x4 hv = *(const f16x4*)(hp + (size_t)q * SS);
    const float ws = sa[q], wd = sd[q];
#pragma unroll
    for (int r = 0; r < 4; ++r) {
      const float hf = (float)hv[r];
      as[r] = fmaf(hf, ws, as[r]);
      ad[r] = fmaf(hf, wd, ad[r]);
    }
  }
  const size_t o = (size_t)dc * 16384 + (b << 10) + s4;
  *(float4*)&psi[o] = *(float4*)as;
  *(float4*)&psj[o] = *(float4*)ad;
}

__global__ __launch_bounds__(256) void rowcomb_k(const float* __restrict__ psi,
                                                 const float* __restrict__ psj,
                                                 float* __restrict__ si,
                                                 float* __restrict__ sj) {
  const int idx = blockIdx.x * 256 + threadIdx.x;  // b*1024 + s
  float a = 0.f, d = 0.f;
#pragma unroll
  for (int c = 0; c < 16; ++c) {
    a += psi[(size_t)c * 16384 + idx];
    d += psj[(size_t)c * 16384 + idx];
  }
  si[idx] = a;
  sj[idx] = d;
}

// ---------------------------------------------------------------------------
// colpre: per batch b, maxsi = max_i si[b][i]; then per j:
//   sjc[b][j] = sj[b][j] + ab ;  refj[b][j] = lrelu(maxsi + sjc)
// (valid softmax shift: lrelu monotone, maxsi >= any unmasked si)
// ---------------------------------------------------------------------------
__global__ __launch_bounds__(256) void colpre_k(const float* __restrict__ si,
                                                const float* __restrict__ sj,
                                                const float* __restrict__ Abp,
                                                float* __restrict__ sjc,
                                                float* __restrict__ refj) {
  const int b = blockIdx.x;
  const int t = threadIdx.x;
  __shared__ float red[256];
  float m = -1e30f;
#pragma unroll
  for (int q = 0; q < 4; ++q) m = fmaxf(m, si[(b << 10) + t + (q << 8)]);
  red[t] = m;
  __syncthreads();
  for (int off = 128; off > 0; off >>= 1) {
    if (t < off) red[t] = fmaxf(red[t], red[t + off]);
    __syncthreads();
  }
  const float maxsi = red[0];
  const float ab = Abp[0];
#pragma unroll
  for (int q = 0; q < 4; ++q) {
    const int j = t + (q << 8);
    const float c = sj[(b << 10) + j] + ab;
    sjc[(b << 10) + j] = c;
    refj[(b << 10) + j] = lrelu(maxsi + c);
  }
}

// ---------------------------------------------------------------------------
// colsum: column partial sums of exp(lrelu(si+sjc)-refj) over masked i.
// block (g: 32 rows, b); thread: byte jb (8 j's), half-row-group; 16 rows.
// pden[(g*2+half)][b*1024+j]
// ---------------------------------------------------------------------------
__global__ __launch_bounds__(256) void colsum_k(
    const unsigned char* __restrict__ bm, const float* __restrict__ si,
    const float* __restrict__ sjc, const float* __restrict__ refj,
    float* __restrict__ pden) {
  const int g = blockIdx.x;  // 0..31
  const int b = blockIdx.y;  // 0..15
  const int t = threadIdx.x;
  const int jb = t & 127;
  const int half = t >> 7;
  const int row0 = (g << 5) + (half << 4);
  __shared__ float s_si[32];
  if (t < 32) s_si[t] = si[(b << 10) + (g << 5) + t];
  __syncthreads();
  float sc[8], rf[8];
  *(float4*)&sc[0] = *(const float4*)&sjc[(b << 10) + jb * 8];
  *(float4*)&sc[4] = *(const float4*)&sjc[(b << 10) + jb * 8 + 4];
  *(float4*)&rf[0] = *(const float4*)&refj[(b << 10) + jb * 8];
  *(float4*)&rf[4] = *(const float4*)&refj[(b << 10) + jb * 8 + 4];
  float den[8] = {0.f, 0.f, 0.f, 0.f, 0.f, 0.f, 0.f, 0.f};
  const unsigned char* bp = bm + ((size_t)b << 17) + ((size_t)row0 << 7) + jb;
#pragma unroll 4
  for (int r = 0; r < 16; ++r) {
    const unsigned m = bp[(size_t)r << 7];
    const float siv = s_si[(half << 4) + r];
#pragma unroll
    for (int k = 0; k < 8; ++k) {
      if ((m >> k) & 1) den[k] += __expf(lrelu(siv + sc[k]) - rf[k]);
    }
  }
  const size_t o = ((size_t)(g * 2 + half)) * 16384 + (b << 10) + jb * 8;
  *(float4*)&pden[o] = *(float4*)&den[0];
  *(float4*)&pden[o + 4] = *(float4*)&den[4];
}

// combine 64 chunks -> rden (sentinel -1 for fully-masked column)
__global__ __launch_bounds__(256) void colcomb_k(const float* __restrict__ pden,
                                                 float* __restrict__ rden) {
  const int idx = blockIdx.x * 256 + threadIdx.x;  // b*1024 + j
  float s = 0.f;
#pragma unroll
  for (int c = 0; c < 64; ++c) s += pden[(size_t)c * 16384 + idx];
  rden[idx] = (s > 0.f) ? 1.f / s : -1.f;
}

// ---------------------------------------------------------------------------
// punorm2: P16[b][i][j] = normalized attention weight (f16), single bitmask
// pass. rden<0 sentinel => uniform column 1/S (reference's all-masked case).
// ---------------------------------------------------------------------------
__global__ __launch_bounds__(256) void punorm2_k(
    const unsigned char* __restrict__ bm, const float* __restrict__ si,
    const float* __restrict__ sjc, const float* __restrict__ refj,
    const float* __restrict__ rden, _Float16* __restrict__ P16) {
  const int g = blockIdx.x;  // 0..31
  const int b = blockIdx.y;  // 0..15
  const int t = threadIdx.x;
  const int jb = t & 127;
  const int half = t >> 7;
  const int row0 = (g << 5) + (half << 4);
  __shared__ float s_si[32];
  if (t < 32) s_si[t] = si[(b << 10) + (g << 5) + t];
  __syncthreads();
  float sc[8], rf[8], rd[8];
  *(float4*)&sc[0] = *(const float4*)&sjc[(b << 10) + jb * 8];
  *(float4*)&sc[4] = *(const float4*)&sjc[(b << 10) + jb * 8 + 4];
  *(float4*)&rf[0] = *(const float4*)&refj[(b << 10) + jb * 8];
  *(float4*)&rf[4] = *(const float4*)&refj[(b << 10) + jb * 8 + 4];
  *(float4*)&rd[0] = *(const float4*)&rden[(b << 10) + jb * 8];
  *(float4*)&rd[4] = *(const float4*)&rden[(b << 10) + jb * 8 + 4];
  const unsigned char* bp = bm + ((size_t)b << 17) + ((size_t)row0 << 7) + jb;
  _Float16* pp = P16 + ((size_t)b << 20) + ((size_t)row0 << 10) + jb * 8;
#pragma unroll 4
  for (int r = 0; r < 16; ++r) {
    const unsigned m = bp[(size_t)r << 7];
    const float siv = s_si[(half << 4) + r];
    f16x8 ph;
#pragma unroll
    for (int k = 0; k < 8; ++k) {
      float p;
      if (rd[k] < 0.f)
        p = 0.0009765625f;  // 1/1024 uniform (all-masked column)
      else if ((m >> k) & 1)
        p = __expf(lrelu(siv + sc[k]) - rf[k]) * rd[k];
      else
        p = 0.f;
      ph[k] = (_Float16)p;
    }
    *(f16x8*)(pp + ((size_t)r << 10)) = ph;
  }
}

// ---------------------------------------------------------------------------
// GEMM2: out[b,i,d] = sum_j P16[b,i,j] * hT16[b,d,j]   (K=1024)
// ---------------------------------------------------------------------------
__global__ __launch_bounds__(256) void gemm2_k(
    const _Float16* __restrict__ P16, const _Float16* __restrict__ hT16,
    float* __restrict__ outl, _Float16* __restrict__ X16n, int writeX) {
  __shared__ _Float16 sA[128 * 32];
  __shared__ _Float16 sB[128 * 32];
  const int i0 = blockIdx.x * 128;
  const int d0 = blockIdx.y * 128;
  const int b = blockIdx.z;
  const int t = threadIdx.x;
  const int w = t >> 6, lane = t & 63;
  const int wr = w >> 1, wc = w & 1;

  f32x4 acc[4][4];
#pragma unroll
  for (int mi = 0; mi < 4; ++mi)
#pragma unroll
    for (int ni = 0; ni < 4; ++ni) acc[mi][ni] = (f32x4)(0.f);

  const _Float16* Pb = P16 + ((size_t)b << 20);
  const _Float16* hTb = hT16 + (size_t)b * DF * SS;
  const int srow = w * 32 + (lane >> 2);
  const int scol = (lane & 3) * 8;

  for (int k0 = 0; k0 < SS; k0 += 32) {
#pragma unroll
    for (int q = 0; q < 2; ++q) {
      int row = srow + q * 16;
      gload16(&Pb[((size_t)(i0 + row) << 10) + k0 + scol],
              (char*)sA + w * 2048 + q * 1024);
      gload16(&hTb[(size_t)(d0 + row) * SS + k0 + scol],
              (char*)sB + w * 2048 + q * 1024);
    }
    __syncthreads();
    f16x8 af[4], bf[4];
#pragma unroll
    for (int mi = 0; mi < 4; ++mi)
      af[mi] = *(const f16x8*)&sA[(wr * 64 + mi * 16 + (lane & 15)) * 32 +
                                  (lane >> 4) * 8];
#pragma unroll
    for (int ni = 0; ni < 4; ++ni)
      bf[ni] = *(const f16x8*)&sB[(wc * 64 + ni * 16 + (lane & 15)) * 32 +
                                  (lane >> 4) * 8];
#pragma unroll
    for (int mi = 0; mi < 4; ++mi)
#pragma unroll
      for (int ni = 0; ni < 4; ++ni)
        acc[mi][ni] = __builtin_amdgcn_mfma_f32_16x16x32_f16(
            af[mi], bf[ni], acc[mi][ni], 0, 0, 0);
    __syncthreads();
  }

  const int cg = lane >> 4, cr = lane & 15;
#pragma unroll
  for (int mi = 0; mi < 4; ++mi) {
#pragma unroll
    for (int ni = 0; ni < 4; ++ni) {
      const int d = d0 + wc * 64 + ni * 16 + cr;
      const int row0 = i0 + wr * 64 + mi * 16 + cg * 4;
#pragma unroll
      for (int r = 0; r < 4; ++r) {
        float v = acc[mi][ni][r];
        size_t o = ((size_t)b * SS + row0 + r) * DF + d;
        outl[o] = v;
        if (writeX) X16n[o] = (_Float16)v;
      }
    }
  }
}

// ---------------------------------------------------------------------------
extern "C" void kernel_launch(void* const* d_in, const int* in_sizes, int n_in,
                              void* d_out, int out_size, void* d_ws,
                              size_t ws_size, hipStream_t stream) {
  const float* X0 = (const float*)d_in[0];
  const int* mask = (const int*)d_in[1];
  const float* W = (const float*)d_in[2];
  const float* Wb = (const float*)d_in[3];
  const float* A = (const float*)d_in[4];
  const float* Ab = (const float*)d_in[5];
  float* out = (float*)d_out;

  const size_t BSD = (size_t)NBATCH * SS * DF;  // 12,582,912 elems
  const size_t BSS = (size_t)NBATCH * SS * SS;  // 16,777,216 elems
  const size_t BS = (size_t)NBATCH * SS;        // 16,384 elems

  char* p = (char*)d_ws;
  _Float16* X16 = (_Float16*)p;   p += BSD * 2;         // 24 MB
  _Float16* hT16 = (_Float16*)p;  p += BSD * 2;         // 24 MB
  _Float16* P16 = (_Float16*)p;   p += BSS * 2;         // 32 MB
  _Float16* W16 = (_Float16*)p;   p += (size_t)2 * DF * DF * 2;  // 2.25 MB
  unsigned char* bmk = (unsigned char*)p; p += BSS / 8;  // 2 MB
  float* psi = (float*)p;  p += 16 * BS * 4;  // 1 MB
  float* psj = (float*)p;  p += 16 * BS * 4;  // 1 MB
  float* pden = (float*)p; p += 64 * BS * 4;  // 4 MB
  float* si = (float*)p;   p += BS * 4;
  float* sj = (float*)p;   p += BS * 4;
  float* sjc = (float*)p;  p += BS * 4;
  float* refj = (float*)p; p += BS * 4;
  float* rden = (float*)p; p += BS * 4;

  f32tof16_k<<<12288, 256, 0, stream>>>(X0, X16, (int)BSD);
  f32tof16_k<<<1152, 256, 0, stream>>>(W, W16, 2 * DF * DF);
  pack_k<<<8192, 256, 0, stream>>>(mask, bmk);

  for (int l = 0; l < 2; ++l) {
    gemm1_k<<<dim3(128, 6), 256, 0, stream>>>(X16, W16 + (size_t)l * DF * DF,
                                              Wb + (size_t)l * DF, hT16);
    rowdots2_k<<<dim3(16, 16), 256, 0, stream>>>(hT16, A + (size_t)l * 2 * DF,
                                                 psi, psj);
    rowcomb_k<<<64, 256, 0, stream>>>(psi, psj, si, sj);
    colpre_k<<<16, 256, 0, stream>>>(si, sj, Ab + l, sjc, refj);
    colsum_k<<<dim3(32, 16), 256, 0, stream>>>(bmk, si, sjc, refj, pden);
    colcomb_k<<<64, 256, 0, stream>>>(pden, rden);
    punorm2_k<<<dim3(32, 16), 256, 0, stream>>>(bmk, si, sjc, refj, rden, P16);
    gemm2_k<<<dim3(8, 6, 16), 256, 0, stream>>>(P16, hT16,
                                                out + (size_t)l * BSD, X16,
                                                (l == 0) ? 1 : 0);
  }
}

// Round 6
// 302.989 us; speedup vs baseline: 1.0669x; 1.0669x over previous
//
#include <hip/hip_runtime.h>
#include <cstddef>

#define SS 1024
#define DF 768
#define NBATCH 16
#define GAT_ALPHA 0.2f

typedef _Float16 f16x8 __attribute__((ext_vector_type(8)));
typedef _Float16 f16x4 __attribute__((ext_vector_type(4)));
typedef float f32x4 __attribute__((ext_vector_type(4)));

// async global->LDS, 16B per lane. LDS dest is wave-uniform base + lane*16.
__device__ __forceinline__ void gload16(const void* g, void* l) {
  __builtin_amdgcn_global_load_lds(
      (const __attribute__((address_space(1))) void*)g,
      (__attribute__((address_space(3))) void*)l, 16, 0, 0);
}

__device__ __forceinline__ float lrelu(float t) {
  return fmaxf(t, GAT_ALPHA * t);
}

// ---------------------------------------------------------------------------
// fp32 -> fp16 convert, 4 elems/thread
// ---------------------------------------------------------------------------
__global__ __launch_bounds__(256) void f32tof16_k(const float* __restrict__ in,
                                                  _Float16* __restrict__ out,
                                                  int n) {
  int idx = (blockIdx.x * 256 + threadIdx.x) * 4;
  if (idx + 3 < n) {
    float4 v = *(const float4*)&in[idx];
    f16x4 o;
    o[0] = (_Float16)v.x;
    o[1] = (_Float16)v.y;
    o[2] = (_Float16)v.z;
    o[3] = (_Float16)v.w;
    *(f16x4*)&out[idx] = o;
  }
}

// ---------------------------------------------------------------------------
// pack: int32 mask (64MB) -> bitmask (2MB). byte t holds j=8t..8t+7 (bit k).
// ---------------------------------------------------------------------------
__global__ __launch_bounds__(256) void pack_k(const int* __restrict__ mask,
                                              unsigned char* __restrict__ bm) {
  const size_t t = (size_t)blockIdx.x * 256 + threadIdx.x;  // byte idx, 2M
  const int* mp = mask + t * 8;
  const int4 a = *(const int4*)mp;
  const int4 c = *(const int4*)(mp + 4);
  unsigned v = (unsigned)(a.x > 0) | ((unsigned)(a.y > 0) << 1) |
               ((unsigned)(a.z > 0) << 2) | ((unsigned)(a.w > 0) << 3) |
               ((unsigned)(c.x > 0) << 4) | ((unsigned)(c.y > 0) << 5) |
               ((unsigned)(c.z > 0) << 6) | ((unsigned)(c.w > 0) << 7);
  bm[t] = (unsigned char)v;
}

// ---------------------------------------------------------------------------
// GEMM1: hT16[b][n][s] = f16( sum_k X16[m,k]*W16[n,k] + Wb[n] ),  m=b*1024+s
// 128x128 tile, BK=32, double-buffered LDS (2-phase: stage t+1 under MFMA t).
// ---------------------------------------------------------------------------
__global__ __launch_bounds__(256) void gemm1_k(
    const _Float16* __restrict__ X16, const _Float16* __restrict__ W16,
    const float* __restrict__ Wbl, _Float16* __restrict__ hT16) {
  __shared__ _Float16 sA[2][128 * 32];
  __shared__ _Float16 sB[2][128 * 32];
  // XCD-chunked swizzle; grid (128,6) = 768 blocks, 768 % 8 == 0
  const int flat = blockIdx.x + 128 * blockIdx.y;
  const int swz = (flat & 7) * 96 + (flat >> 3);
  const int m0 = (swz & 127) * 128;
  const int n0 = (swz >> 7) * 128;
  const int t = threadIdx.x;
  const int w = t >> 6, lane = t & 63;
  const int wr = w >> 1, wc = w & 1;

  f32x4 acc[4][4];
#pragma unroll
  for (int mi = 0; mi < 4; ++mi)
#pragma unroll
    for (int ni = 0; ni < 4; ++ni) acc[mi][ni] = (f32x4)(0.f);

  const int srow = w * 32 + (lane >> 2);
  const int scol = (lane & 3) * 8;

#define STAGE1(bufi, k0)                                             \
  {                                                                  \
    _Pragma("unroll") for (int q = 0; q < 2; ++q) {                  \
      int row = srow + q * 16;                                       \
      gload16(&X16[(size_t)(m0 + row) * DF + (k0) + scol],           \
              (char*)sA[bufi] + w * 2048 + q * 1024);                \
      gload16(&W16[(size_t)(n0 + row) * DF + (k0) + scol],           \
              (char*)sB[bufi] + w * 2048 + q * 1024);                \
    }                                                                \
  }

  STAGE1(0, 0);
  int cur = 0;
  for (int kt = 0; kt < DF / 32; ++kt) {
    __syncthreads();  // drains vmcnt: buf[cur] ready; all reads of buf[cur^1] done
    if (kt + 1 < DF / 32) STAGE1(cur ^ 1, (kt + 1) * 32);
    f16x8 af[4], bf[4];
#pragma unroll
    for (int mi = 0; mi < 4; ++mi)
      af[mi] = *(const f16x8*)&sA[cur][(wr * 64 + mi * 16 + (lane & 15)) * 32 +
                                       (lane >> 4) * 8];
#pragma unroll
    for (int ni = 0; ni < 4; ++ni)
      bf[ni] = *(const f16x8*)&sB[cur][(wc * 64 + ni * 16 + (lane & 15)) * 32 +
                                       (lane >> 4) * 8];
#pragma unroll
    for (int mi = 0; mi < 4; ++mi)
#pragma unroll
      for (int ni = 0; ni < 4; ++ni)
        acc[mi][ni] = __builtin_amdgcn_mfma_f32_16x16x32_f16(
            af[mi], bf[ni], acc[mi][ni], 0, 0, 0);
    cur ^= 1;
  }
#undef STAGE1

  const int cg = lane >> 4, cr = lane & 15;
#pragma unroll
  for (int mi = 0; mi < 4; ++mi) {
#pragma unroll
    for (int ni = 0; ni < 4; ++ni) {
      const int col = n0 + wc * 64 + ni * 16 + cr;
      const float bias = Wbl[col];
      const int row0 = m0 + wr * 64 + mi * 16 + cg * 4;
      f16x4 tv;
#pragma unroll
      for (int r = 0; r < 4; ++r) tv[r] = (_Float16)(acc[mi][ni][r] + bias);
      const int bb = row0 >> 10, s0 = row0 & 1023;
      *(f16x4*)&hT16[((size_t)bb * DF + col) * SS + s0] = tv;
    }
  }
}

// ---------------------------------------------------------------------------
// rowdots2: si/sj partials from hT16 (coalesced: thread owns 4 consecutive s,
// loops d within its chunk). psi/psj[dc][b*1024+s], combined by rowfin.
// ---------------------------------------------------------------------------
__global__ __launch_bounds__(256) void rowdots2_k(
    const _Float16* __restrict__ hT, const float* __restrict__ Al,
    float* __restrict__ psi, float* __restrict__ psj) {
  const int dc = blockIdx.x;  // 0..15 (48 d's each)
  const int b = blockIdx.y;   // 0..15
  const int t = threadIdx.x;
  const int s4 = t * 4;
  __shared__ float sa[48], sd[48];
  if (t < 48) {
    sa[t] = Al[dc * 48 + t];
    sd[t] = Al[DF + dc * 48 + t];
  }
  __syncthreads();
  float as[4] = {0.f, 0.f, 0.f, 0.f}, ad[4] = {0.f, 0.f, 0.f, 0.f};
  const _Float16* hp = hT + ((size_t)b * DF + dc * 48) * SS + s4;
#pragma unroll 4
  for (int q = 0; q < 48; ++q) {
    const f16x4 hv = *(const f16x4*)(hp + (size_t)q * SS);
    const float ws = sa[q], wd = sd[q];
#pragma unroll
    for (int r = 0; r < 4; ++r) {
      const float hf = (float)hv[r];
      as[r] = fmaf(hf, ws, as[r]);
      ad[r] = fmaf(hf, wd, ad[r]);
    }
  }
  const size_t o = (size_t)dc * 16384 + (b << 10) + s4;
  *(float4*)&psi[o] = *(float4*)as;
  *(float4*)&psj[o] = *(float4*)ad;
}

// ---------------------------------------------------------------------------
// rowfin: combine psi/psj chunks -> si; per-batch max(si); sjc/refj.
// one block per batch.
// ---------------------------------------------------------------------------
__global__ __launch_bounds__(256) void rowfin_k(const float* __restrict__ psi,
                                                const float* __restrict__ psj,
                                                const float* __restrict__ Abp,
                                                float* __restrict__ si,
                                                float* __restrict__ sjc,
                                                float* __restrict__ refj) {
  const int b = blockIdx.x;
  const int t = threadIdx.x;
  __shared__ float red[256];
  float siv[4], sjv[4];
  float mloc = -1e30f;
#pragma unroll
  for (int q = 0; q < 4; ++q) {
    const int idx = (b << 10) + t + (q << 8);
    float a = 0.f, d = 0.f;
#pragma unroll
    for (int c = 0; c < 16; ++c) {
      a += psi[(size_t)c * 16384 + idx];
      d += psj[(size_t)c * 16384 + idx];
    }
    siv[q] = a;
    sjv[q] = d;
    si[idx] = a;
    mloc = fmaxf(mloc, a);
  }
  red[t] = mloc;
  __syncthreads();
  for (int off = 128; off > 0; off >>= 1) {
    if (t < off) red[t] = fmaxf(red[t], red[t + off]);
    __syncthreads();
  }
  const float maxsi = red[0];
  const float ab = Abp[0];
#pragma unroll
  for (int q = 0; q < 4; ++q) {
    const int idx = (b << 10) + t + (q << 8);
    const float c = sjv[q] + ab;
    sjc[idx] = c;
    refj[idx] = lrelu(maxsi + c);
  }
}

// ---------------------------------------------------------------------------
// colsum: column partial sums of exp(lrelu(si+sjc)-refj) over masked i.
// block (g: 32 rows, b); thread: byte jb (8 j's), half-row-group; 16 rows.
// ---------------------------------------------------------------------------
__global__ __launch_bounds__(256) void colsum_k(
    const unsigned char* __restrict__ bm, const float* __restrict__ si,
    const float* __restrict__ sjc, const float* __restrict__ refj,
    float* __restrict__ pden) {
  const int g = blockIdx.x;  // 0..31
  const int b = blockIdx.y;  // 0..15
  const int t = threadIdx.x;
  const int jb = t & 127;
  const int half = t >> 7;
  const int row0 = (g << 5) + (half << 4);
  __shared__ float s_si[32];
  if (t < 32) s_si[t] = si[(b << 10) + (g << 5) + t];
  __syncthreads();
  float sc[8], rf[8];
  *(float4*)&sc[0] = *(const float4*)&sjc[(b << 10) + jb * 8];
  *(float4*)&sc[4] = *(const float4*)&sjc[(b << 10) + jb * 8 + 4];
  *(float4*)&rf[0] = *(const float4*)&refj[(b << 10) + jb * 8];
  *(float4*)&rf[4] = *(const float4*)&refj[(b << 10) + jb * 8 + 4];
  float den[8] = {0.f, 0.f, 0.f, 0.f, 0.f, 0.f, 0.f, 0.f};
  const unsigned char* bp = bm + ((size_t)b << 17) + ((size_t)row0 << 7) + jb;
#pragma unroll 4
  for (int r = 0; r < 16; ++r) {
    const unsigned m = bp[(size_t)r << 7];
    const float siv = s_si[(half << 4) + r];
#pragma unroll
    for (int k = 0; k < 8; ++k) {
      if ((m >> k) & 1) den[k] += __expf(lrelu(siv + sc[k]) - rf[k]);
    }
  }
  const size_t o = ((size_t)(g * 2 + half)) * 16384 + (b << 10) + jb * 8;
  *(float4*)&pden[o] = *(float4*)&den[0];
  *(float4*)&pden[o + 4] = *(float4*)&den[4];
}

// combine 64 chunks -> rden (sentinel -1 for fully-masked column)
__global__ __launch_bounds__(256) void colcomb_k(const float* __restrict__ pden,
                                                 float* __restrict__ rden) {
  const int idx = blockIdx.x * 256 + threadIdx.x;  // b*1024 + j
  float s = 0.f;
#pragma unroll
  for (int c = 0; c < 64; ++c) s += pden[(size_t)c * 16384 + idx];
  rden[idx] = (s > 0.f) ? 1.f / s : -1.f;
}

// ---------------------------------------------------------------------------
// punorm2: P16[b][i][j] = normalized attention weight (f16), single bitmask
// pass. rden<0 sentinel => uniform column 1/S (reference's all-masked case).
// ---------------------------------------------------------------------------
__global__ __launch_bounds__(256) void punorm2_k(
    const unsigned char* __restrict__ bm, const float* __restrict__ si,
    const float* __restrict__ sjc, const float* __restrict__ refj,
    const float* __restrict__ rden, _Float16* __restrict__ P16) {
  const int g = blockIdx.x;  // 0..31
  const int b = blockIdx.y;  // 0..15
  const int t = threadIdx.x;
  const int jb = t & 127;
  const int half = t >> 7;
  const int row0 = (g << 5) + (half << 4);
  __shared__ float s_si[32];
  if (t < 32) s_si[t] = si[(b << 10) + (g << 5) + t];
  __syncthreads();
  float sc[8], rf[8], rd[8];
  *(float4*)&sc[0] = *(const float4*)&sjc[(b << 10) + jb * 8];
  *(float4*)&sc[4] = *(const float4*)&sjc[(b << 10) + jb * 8 + 4];
  *(float4*)&rf[0] = *(const float4*)&refj[(b << 10) + jb * 8];
  *(float4*)&rf[4] = *(const float4*)&refj[(b << 10) + jb * 8 + 4];
  *(float4*)&rd[0] = *(const float4*)&rden[(b << 10) + jb * 8];
  *(float4*)&rd[4] = *(const float4*)&rden[(b << 10) + jb * 8 + 4];
  const unsigned char* bp = bm + ((size_t)b << 17) + ((size_t)row0 << 7) + jb;
  _Float16* pp = P16 + ((size_t)b << 20) + ((size_t)row0 << 10) + jb * 8;
#pragma unroll 4
  for (int r = 0; r < 16; ++r) {
    const unsigned m = bp[(size_t)r << 7];
    const float siv = s_si[(half << 4) + r];
    f16x8 ph;
#pragma unroll
    for (int k = 0; k < 8; ++k) {
      float p;
      if (rd[k] < 0.f)
        p = 0.0009765625f;  // 1/1024 uniform (all-masked column)
      else if ((m >> k) & 1)
        p = __expf(lrelu(siv + sc[k]) - rf[k]) * rd[k];
      else
        p = 0.f;
      ph[k] = (_Float16)p;
    }
    *(f16x8*)(pp + ((size_t)r << 10)) = ph;
  }
}

// ---------------------------------------------------------------------------
// GEMM2: out[b,i,d] = sum_j P16[b,i,j] * hT16[b,d,j]   (K=1024)
// 128x128 tile, BK=32, double-buffered LDS, XCD-chunked swizzle.
// ---------------------------------------------------------------------------
__global__ __launch_bounds__(256) void gemm2_k(
    const _Float16* __restrict__ P16, const _Float16* __restrict__ hT16,
    float* __restrict__ outl, _Float16* __restrict__ X16n, int writeX) {
  __shared__ _Float16 sA[2][128 * 32];
  __shared__ _Float16 sB[2][128 * 32];
  // XCD-chunked swizzle; grid (8,6,16) = 768 blocks. Each XCD gets 96
  // consecutive swz = 2 batches (~7MB) -> L2-resident working set.
  const int flat = blockIdx.x + 8 * (blockIdx.y + 6 * blockIdx.z);
  const int swz = (flat & 7) * 96 + (flat >> 3);
  const int i0 = (swz & 7) * 128;
  const int d0 = ((swz >> 3) % 6) * 128;
  const int b = swz / 48;
  const int t = threadIdx.x;
  const int w = t >> 6, lane = t & 63;
  const int wr = w >> 1, wc = w & 1;

  f32x4 acc[4][4];
#pragma unroll
  for (int mi = 0; mi < 4; ++mi)
#pragma unroll
    for (int ni = 0; ni < 4; ++ni) acc[mi][ni] = (f32x4)(0.f);

  const _Float16* Pb = P16 + ((size_t)b << 20);
  const _Float16* hTb = hT16 + (size_t)b * DF * SS;
  const int srow = w * 32 + (lane >> 2);
  const int scol = (lane & 3) * 8;

#define STAGE2(bufi, k0)                                             \
  {                                                                  \
    _Pragma("unroll") for (int q = 0; q < 2; ++q) {                  \
      int row = srow + q * 16;                                       \
      gload16(&Pb[((size_t)(i0 + row) << 10) + (k0) + scol],         \
              (char*)sA[bufi] + w * 2048 + q * 1024);                \
      gload16(&hTb[(size_t)(d0 + row) * SS + (k0) + scol],           \
              (char*)sB[bufi] + w * 2048 + q * 1024);                \
    }                                                                \
  }

  STAGE2(0, 0);
  int cur = 0;
  for (int kt = 0; kt < SS / 32; ++kt) {
    __syncthreads();
    if (kt + 1 < SS / 32) STAGE2(cur ^ 1, (kt + 1) * 32);
    f16x8 af[4], bf[4];
#pragma unroll
    for (int mi = 0; mi < 4; ++mi)
      af[mi] = *(const f16x8*)&sA[cur][(wr * 64 + mi * 16 + (lane & 15)) * 32 +
                                       (lane >> 4) * 8];
#pragma unroll
    for (int ni = 0; ni < 4; ++ni)
      bf[ni] = *(const f16x8*)&sB[cur][(wc * 64 + ni * 16 + (lane & 15)) * 32 +
                                       (lane >> 4) * 8];
#pragma unroll
    for (int mi = 0; mi < 4; ++mi)
#pragma unroll
      for (int ni = 0; ni < 4; ++ni)
        acc[mi][ni] = __builtin_amdgcn_mfma_f32_16x16x32_f16(
            af[mi], bf[ni], acc[mi][ni], 0, 0, 0);
    cur ^= 1;
  }
#undef STAGE2

  const int cg = lane >> 4, cr = lane & 15;
#pragma unroll
  for (int mi = 0; mi < 4; ++mi) {
#pragma unroll
    for (int ni = 0; ni < 4; ++ni) {
      const int d = d0 + wc * 64 + ni * 16 + cr;
      const int row0 = i0 + wr * 64 + mi * 16 + cg * 4;
#pragma unroll
      for (int r = 0; r < 4; ++r) {
        float v = acc[mi][ni][r];
        size_t o = ((size_t)b * SS + row0 + r) * DF + d;
        outl[o] = v;
        if (writeX) X16n[o] = (_Float16)v;
      }
    }
  }
}

// ---------------------------------------------------------------------------
extern "C" void kernel_launch(void* const* d_in, const int* in_sizes, int n_in,
                              void* d_out, int out_size, void* d_ws,
                              size_t ws_size, hipStream_t stream) {
  const float* X0 = (const float*)d_in[0];
  const int* mask = (const int*)d_in[1];
  const float* W = (const float*)d_in[2];
  const float* Wb = (const float*)d_in[3];
  const float* A = (const float*)d_in[4];
  const float* Ab = (const float*)d_in[5];
  float* out = (float*)d_out;

  const size_t BSD = (size_t)NBATCH * SS * DF;  // 12,582,912 elems
  const size_t BSS = (size_t)NBATCH * SS * SS;  // 16,777,216 elems
  const size_t BS = (size_t)NBATCH * SS;        // 16,384 elems

  char* p = (char*)d_ws;
  _Float16* X16 = (_Float16*)p;   p += BSD * 2;                   // 24 MB
  _Float16* hT16 = (_Float16*)p;  p += BSD * 2;                   // 24 MB
  _Float16* P16 = (_Float16*)p;   p += BSS * 2;                   // 32 MB
  _Float16* W16 = (_Float16*)p;   p += (size_t)2 * DF * DF * 2;   // 2.25 MB
  unsigned char* bmk = (unsigned char*)p; p += BSS / 8;           // 2 MB
  float* psi = (float*)p;  p += 16 * BS * 4;  // 1 MB
  float* psj = (float*)p;  p += 16 * BS * 4;  // 1 MB
  float* pden = (float*)p; p += 64 * BS * 4;  // 4 MB
  float* si = (float*)p;   p += BS * 4;
  float* sjc = (float*)p;  p += BS * 4;
  float* refj = (float*)p; p += BS * 4;
  float* rden = (float*)p; p += BS * 4;

  f32tof16_k<<<12288, 256, 0, stream>>>(X0, X16, (int)BSD);
  f32tof16_k<<<1152, 256, 0, stream>>>(W, W16, 2 * DF * DF);
  pack_k<<<8192, 256, 0, stream>>>(mask, bmk);

  for (int l = 0; l < 2; ++l) {
    gemm1_k<<<dim3(128, 6), 256, 0, stream>>>(X16, W16 + (size_t)l * DF * DF,
                                              Wb + (size_t)l * DF, hT16);
    rowdots2_k<<<dim3(16, 16), 256, 0, stream>>>(hT16, A + (size_t)l * 2 * DF,
                                                 psi, psj);
    rowfin_k<<<16, 256, 0, stream>>>(psi, psj, Ab + l, si, sjc, refj);
    colsum_k<<<dim3(32, 16), 256, 0, stream>>>(bmk, si, sjc, refj, pden);
    colcomb_k<<<64, 256, 0, stream>>>(pden, rden);
    punorm2_k<<<dim3(32, 16), 256, 0, stream>>>(bmk, si, sjc, refj, rden, P16);
    gemm2_k<<<dim3(8, 6, 16), 256, 0, stream>>>(P16, hT16,
                                                out + (size_t)l * BSD, X16,
                                                (l == 0) ? 1 : 0);
  }
}

// Round 7
// 285.928 us; speedup vs baseline: 1.1305x; 1.0597x over previous
//
#include <hip/hip_runtime.h>
#include <cstddef>

#define SS 1024
#define DF 768
#define NBATCH 16
#define GAT_ALPHA 0.2f

typedef _Float16 f16x8 __attribute__((ext_vector_type(8)));
typedef _Float16 f16x4 __attribute__((ext_vector_type(4)));
typedef float f32x4 __attribute__((ext_vector_type(4)));

// async global->LDS, 16B per lane. LDS dest is wave-uniform base + lane*16.
__device__ __forceinline__ void gload16(const void* g, void* l) {
  __builtin_amdgcn_global_load_lds(
      (const __attribute__((address_space(1))) void*)g,
      (__attribute__((address_space(3))) void*)l, 16, 0, 0);
}

__device__ __forceinline__ float lrelu(float t) {
  return fmaxf(t, GAT_ALPHA * t);
}

// ---------------------------------------------------------------------------
// fp32 -> fp16 convert, 4 elems/thread
// ---------------------------------------------------------------------------
__global__ __launch_bounds__(256) void f32tof16_k(const float* __restrict__ in,
                                                  _Float16* __restrict__ out,
                                                  int n) {
  int idx = (blockIdx.x * 256 + threadIdx.x) * 4;
  if (idx + 3 < n) {
    float4 v = *(const float4*)&in[idx];
    f16x4 o;
    o[0] = (_Float16)v.x;
    o[1] = (_Float16)v.y;
    o[2] = (_Float16)v.z;
    o[3] = (_Float16)v.w;
    *(f16x4*)&out[idx] = o;
  }
}

// ---------------------------------------------------------------------------
// pack: int32 mask (64MB) -> bitmask (2MB). byte t holds j=8t..8t+7 (bit k).
// ---------------------------------------------------------------------------
__global__ __launch_bounds__(256) void pack_k(const int* __restrict__ mask,
                                              unsigned char* __restrict__ bm) {
  const size_t t = (size_t)blockIdx.x * 256 + threadIdx.x;  // byte idx, 2M
  const int* mp = mask + t * 8;
  const int4 a = *(const int4*)mp;
  const int4 c = *(const int4*)(mp + 4);
  unsigned v = (unsigned)(a.x > 0) | ((unsigned)(a.y > 0) << 1) |
               ((unsigned)(a.z > 0) << 2) | ((unsigned)(a.w > 0) << 3) |
               ((unsigned)(c.x > 0) << 4) | ((unsigned)(c.y > 0) << 5) |
               ((unsigned)(c.z > 0) << 6) | ((unsigned)(c.w > 0) << 7);
  bm[t] = (unsigned char)v;
}

// ---------------------------------------------------------------------------
// GEMM1: hT16[b][n][s] = f16( sum_k X16[m,k]*W16[n,k] + Wb[n] ),  m=b*1024+s
// 128x128 tile, BK=32, 3-slot pipelined LDS, counted vmcnt(4), 1 barrier/step.
// Epilogue transposes C through LDS -> coalesced hT16 writes.
// ---------------------------------------------------------------------------
__global__ __launch_bounds__(256) void gemm1_k(
    const _Float16* __restrict__ X16, const _Float16* __restrict__ W16,
    const float* __restrict__ Wbl, _Float16* __restrict__ hT16) {
  __shared__ __align__(16) char smem[49152];  // 3 slots x (A 8KB + B 8KB)
  const int flat = blockIdx.x + 128 * blockIdx.y;
  const int swz = (flat & 7) * 96 + (flat >> 3);
  const int m0 = (swz & 127) * 128;
  const int n0 = (swz >> 7) * 128;
  const int t = threadIdx.x;
  const int w = t >> 6, lane = t & 63;
  const int wr = w >> 1, wc = w & 1;

  f32x4 acc[4][4];
#pragma unroll
  for (int mi = 0; mi < 4; ++mi)
#pragma unroll
    for (int ni = 0; ni < 4; ++ni) acc[mi][ni] = (f32x4)(0.f);

  const int srow = w * 32 + (lane >> 2);
  const int scol = (lane & 3) * 8;

#define STG1(slot, k0)                                                    \
  {                                                                       \
    _Pragma("unroll") for (int q = 0; q < 2; ++q) {                       \
      int row = srow + q * 16;                                            \
      gload16(&X16[(size_t)(m0 + row) * DF + (k0) + scol],                \
              smem + (slot) * 16384 + w * 2048 + q * 1024);               \
      gload16(&W16[(size_t)(n0 + row) * DF + (k0) + scol],                \
              smem + (slot) * 16384 + 8192 + w * 2048 + q * 1024);        \
    }                                                                     \
  }

  const int NT = DF / 32;  // 24
  STG1(0, 0);
  STG1(1, 32);
  for (int kt = 0; kt < NT; ++kt) {
    if (kt < NT - 1)
      asm volatile("s_waitcnt vmcnt(4) lgkmcnt(0)\ns_barrier" ::: "memory");
    else
      asm volatile("s_waitcnt vmcnt(0) lgkmcnt(0)\ns_barrier" ::: "memory");
    if (kt + 2 < NT) {
      const int sl = (kt + 2) % 3;
      STG1(sl, (kt + 2) * 32);
    }
    const _Float16* As = (const _Float16*)(smem + (kt % 3) * 16384);
    const _Float16* Bs = (const _Float16*)(smem + (kt % 3) * 16384 + 8192);
    f16x8 af[4], bf[4];
#pragma unroll
    for (int mi = 0; mi < 4; ++mi)
      af[mi] = *(const f16x8*)&As[(wr * 64 + mi * 16 + (lane & 15)) * 32 +
                                  (lane >> 4) * 8];
#pragma unroll
    for (int ni = 0; ni < 4; ++ni)
      bf[ni] = *(const f16x8*)&Bs[(wc * 64 + ni * 16 + (lane & 15)) * 32 +
                                  (lane >> 4) * 8];
#pragma unroll
    for (int mi = 0; mi < 4; ++mi)
#pragma unroll
      for (int ni = 0; ni < 4; ++ni)
        acc[mi][ni] = __builtin_amdgcn_mfma_f32_16x16x32_f16(
            af[mi], bf[ni], acc[mi][ni], 0, 0, 0);
  }
#undef STG1

  // epilogue: transpose via LDS (stride 136 to spread banks), coalesced write
  __syncthreads();
  _Float16* tb = (_Float16*)smem;  // [128 cols][136]
  const int cg = lane >> 4, cr = lane & 15;
#pragma unroll
  for (int ni = 0; ni < 4; ++ni) {
    const int col = wc * 64 + ni * 16 + cr;
    const float bias = Wbl[n0 + col];
#pragma unroll
    for (int mi = 0; mi < 4; ++mi) {
      const int row = wr * 64 + mi * 16 + cg * 4;
      f16x4 tv;
#pragma unroll
      for (int r = 0; r < 4; ++r) tv[r] = (_Float16)(acc[mi][ni][r] + bias);
      *(f16x4*)&tb[col * 136 + row] = tv;
    }
  }
  __syncthreads();
  const int bb = m0 >> 10, s0 = m0 & 1023;
#pragma unroll
  for (int pass = 0; pass < 8; ++pass) {
    const int col = pass * 16 + (t >> 4);
    const int chunk = (t & 15) * 8;
    f16x8 v = *(const f16x8*)&tb[col * 136 + chunk];
    *(f16x8*)&hT16[((size_t)bb * DF + n0 + col) * SS + s0 + chunk] = v;
  }
}

// ---------------------------------------------------------------------------
// rowdots2: si/sj partials from hT16 (coalesced), combined by rowfin.
// ---------------------------------------------------------------------------
__global__ __launch_bounds__(256) void rowdots2_k(
    const _Float16* __restrict__ hT, const float* __restrict__ Al,
    float* __restrict__ psi, float* __restrict__ psj) {
  const int dc = blockIdx.x;  // 0..15 (48 d's each)
  const int b = blockIdx.y;   // 0..15
  const int t = threadIdx.x;
  const int s4 = t * 4;
  __shared__ float sa[48], sd[48];
  if (t < 48) {
    sa[t] = Al[dc * 48 + t];
    sd[t] = Al[DF + dc * 48 + t];
  }
  __syncthreads();
  float as[4] = {0.f, 0.f, 0.f, 0.f}, ad[4] = {0.f, 0.f, 0.f, 0.f};
  const _Float16* hp = hT + ((size_t)b * DF + dc * 48) * SS + s4;
#pragma unroll 4
  for (int q = 0; q < 48; ++q) {
    const f16x4 hv = *(const f16x4*)(hp + (size_t)q * SS);
    const float ws = sa[q], wd = sd[q];
#pragma unroll
    for (int r = 0; r < 4; ++r) {
      const float hf = (float)hv[r];
      as[r] = fmaf(hf, ws, as[r]);
      ad[r] = fmaf(hf, wd, ad[r]);
    }
  }
  const size_t o = (size_t)dc * 16384 + (b << 10) + s4;
  *(float4*)&psi[o] = *(float4*)as;
  *(float4*)&psj[o] = *(float4*)ad;
}

// ---------------------------------------------------------------------------
// rowfin: combine psi/psj chunks -> si; per-batch max(si); sjc/refj.
// ---------------------------------------------------------------------------
__global__ __launch_bounds__(256) void rowfin_k(const float* __restrict__ psi,
                                                const float* __restrict__ psj,
                                                const float* __restrict__ Abp,
                                                float* __restrict__ si,
                                                float* __restrict__ sjc,
                                                float* __restrict__ refj) {
  const int b = blockIdx.x;
  const int t = threadIdx.x;
  __shared__ float red[256];
  float siv[4], sjv[4];
  float mloc = -1e30f;
#pragma unroll
  for (int q = 0; q < 4; ++q) {
    const int idx = (b << 10) + t + (q << 8);
    float a = 0.f, d = 0.f;
#pragma unroll
    for (int c = 0; c < 16; ++c) {
      a += psi[(size_t)c * 16384 + idx];
      d += psj[(size_t)c * 16384 + idx];
    }
    siv[q] = a;
    sjv[q] = d;
    si[idx] = a;
    mloc = fmaxf(mloc, a);
  }
  red[t] = mloc;
  __syncthreads();
  for (int off = 128; off > 0; off >>= 1) {
    if (t < off) red[t] = fmaxf(red[t], red[t + off]);
    __syncthreads();
  }
  const float maxsi = red[0];
  const float ab = Abp[0];
#pragma unroll
  for (int q = 0; q < 4; ++q) {
    const int idx = (b << 10) + t + (q << 8);
    const float c = sjv[q] + ab;
    sjc[idx] = c;
    refj[idx] = lrelu(maxsi + c);
  }
}

// ---------------------------------------------------------------------------
// colsum: column partial sums of exp(lrelu(si+sjc)-refj) over masked i.
// ---------------------------------------------------------------------------
__global__ __launch_bounds__(256) void colsum_k(
    const unsigned char* __restrict__ bm, const float* __restrict__ si,
    const float* __restrict__ sjc, const float* __restrict__ refj,
    float* __restrict__ pden) {
  const int g = blockIdx.x;  // 0..31
  const int b = blockIdx.y;  // 0..15
  const int t = threadIdx.x;
  const int jb = t & 127;
  const int half = t >> 7;
  const int row0 = (g << 5) + (half << 4);
  __shared__ float s_si[32];
  if (t < 32) s_si[t] = si[(b << 10) + (g << 5) + t];
  __syncthreads();
  float sc[8], rf[8];
  *(float4*)&sc[0] = *(const float4*)&sjc[(b << 10) + jb * 8];
  *(float4*)&sc[4] = *(const float4*)&sjc[(b << 10) + jb * 8 + 4];
  *(float4*)&rf[0] = *(const float4*)&refj[(b << 10) + jb * 8];
  *(float4*)&rf[4] = *(const float4*)&refj[(b << 10) + jb * 8 + 4];
  float den[8] = {0.f, 0.f, 0.f, 0.f, 0.f, 0.f, 0.f, 0.f};
  const unsigned char* bp = bm + ((size_t)b << 17) + ((size_t)row0 << 7) + jb;
#pragma unroll 4
  for (int r = 0; r < 16; ++r) {
    const unsigned m = bp[(size_t)r << 7];
    const float siv = s_si[(half << 4) + r];
#pragma unroll
    for (int k = 0; k < 8; ++k) {
      if ((m >> k) & 1) den[k] += __expf(lrelu(siv + sc[k]) - rf[k]);
    }
  }
  const size_t o = ((size_t)(g * 2 + half)) * 16384 + (b << 10) + jb * 8;
  *(float4*)&pden[o] = *(float4*)&den[0];
  *(float4*)&pden[o + 4] = *(float4*)&den[4];
}

// combine 64 chunks -> rden (sentinel -1 for fully-masked column)
__global__ __launch_bounds__(256) void colcomb_k(const float* __restrict__ pden,
                                                 float* __restrict__ rden) {
  const int idx = blockIdx.x * 256 + threadIdx.x;  // b*1024 + j
  float s = 0.f;
#pragma unroll
  for (int c = 0; c < 64; ++c) s += pden[(size_t)c * 16384 + idx];
  rden[idx] = (s > 0.f) ? 1.f / s : -1.f;
}

// ---------------------------------------------------------------------------
// punorm2: P16[b][i][j] = normalized attention weight (f16), single bitmask
// pass. rden<0 sentinel => uniform column 1/S (reference's all-masked case).
// ---------------------------------------------------------------------------
__global__ __launch_bounds__(256) void punorm2_k(
    const unsigned char* __restrict__ bm, const float* __restrict__ si,
    const float* __restrict__ sjc, const float* __restrict__ refj,
    const float* __restrict__ rden, _Float16* __restrict__ P16) {
  const int g = blockIdx.x;  // 0..31
  const int b = blockIdx.y;  // 0..15
  const int t = threadIdx.x;
  const int jb = t & 127;
  const int half = t >> 7;
  const int row0 = (g << 5) + (half << 4);
  __shared__ float s_si[32];
  if (t < 32) s_si[t] = si[(b << 10) + (g << 5) + t];
  __syncthreads();
  float sc[8], rf[8], rd[8];
  *(float4*)&sc[0] = *(const float4*)&sjc[(b << 10) + jb * 8];
  *(float4*)&sc[4] = *(const float4*)&sjc[(b << 10) + jb * 8 + 4];
  *(float4*)&rf[0] = *(const float4*)&refj[(b << 10) + jb * 8];
  *(float4*)&rf[4] = *(const float4*)&refj[(b << 10) + jb * 8 + 4];
  *(float4*)&rd[0] = *(const float4*)&rden[(b << 10) + jb * 8];
  *(float4*)&rd[4] = *(const float4*)&rden[(b << 10) + jb * 8 + 4];
  const unsigned char* bp = bm + ((size_t)b << 17) + ((size_t)row0 << 7) + jb;
  _Float16* pp = P16 + ((size_t)b << 20) + ((size_t)row0 << 10) + jb * 8;
#pragma unroll 4
  for (int r = 0; r < 16; ++r) {
    const unsigned m = bp[(size_t)r << 7];
    const float siv = s_si[(half << 4) + r];
    f16x8 ph;
#pragma unroll
    for (int k = 0; k < 8; ++k) {
      float p;
      if (rd[k] < 0.f)
        p = 0.0009765625f;  // 1/1024 uniform (all-masked column)
      else if ((m >> k) & 1)
        p = __expf(lrelu(siv + sc[k]) - rf[k]) * rd[k];
      else
        p = 0.f;
      ph[k] = (_Float16)p;
    }
    *(f16x8*)(pp + ((size_t)r << 10)) = ph;
  }
}

// ---------------------------------------------------------------------------
// GEMM2: out[b,i,d] = sum_j P16[b,i,j] * hT16[b,d,j]   (K=1024)
// 128x128 tile, BK=32, 3-slot pipelined LDS, counted vmcnt(4), XCD swizzle.
// ---------------------------------------------------------------------------
__global__ __launch_bounds__(256) void gemm2_k(
    const _Float16* __restrict__ P16, const _Float16* __restrict__ hT16,
    float* __restrict__ outl, _Float16* __restrict__ X16n, int writeX) {
  __shared__ __align__(16) char smem[49152];  // 3 slots x (A 8KB + B 8KB)
  const int flat = blockIdx.x + 8 * (blockIdx.y + 6 * blockIdx.z);
  const int swz = (flat & 7) * 96 + (flat >> 3);
  const int i0 = (swz & 7) * 128;
  const int d0 = ((swz >> 3) % 6) * 128;
  const int b = swz / 48;
  const int t = threadIdx.x;
  const int w = t >> 6, lane = t & 63;
  const int wr = w >> 1, wc = w & 1;

  f32x4 acc[4][4];
#pragma unroll
  for (int mi = 0; mi < 4; ++mi)
#pragma unroll
    for (int ni = 0; ni < 4; ++ni) acc[mi][ni] = (f32x4)(0.f);

  const _Float16* Pb = P16 + ((size_t)b << 20);
  const _Float16* hTb = hT16 + (size_t)b * DF * SS;
  const int srow = w * 32 + (lane >> 2);
  const int scol = (lane & 3) * 8;

#define STG2(slot, k0)                                                    \
  {                                                                       \
    _Pragma("unroll") for (int q = 0; q < 2; ++q) {                       \
      int row = srow + q * 16;                                            \
      gload16(&Pb[((size_t)(i0 + row) << 10) + (k0) + scol],              \
              smem + (slot) * 16384 + w * 2048 + q * 1024);               \
      gload16(&hTb[(size_t)(d0 + row) * SS + (k0) + scol],                \
              smem + (slot) * 16384 + 8192 + w * 2048 + q * 1024);        \
    }                                                                     \
  }

  const int NT = SS / 32;  // 32
  STG2(0, 0);
  STG2(1, 32);
  for (int kt = 0; kt < NT; ++kt) {
    if (kt < NT - 1)
      asm volatile("s_waitcnt vmcnt(4) lgkmcnt(0)\ns_barrier" ::: "memory");
    else
      asm volatile("s_waitcnt vmcnt(0) lgkmcnt(0)\ns_barrier" ::: "memory");
    if (kt + 2 < NT) {
      const int sl = (kt + 2) % 3;
      STG2(sl, (kt + 2) * 32);
    }
    const _Float16* As = (const _Float16*)(smem + (kt % 3) * 16384);
    const _Float16* Bs = (const _Float16*)(smem + (kt % 3) * 16384 + 8192);
    f16x8 af[4], bf[4];
#pragma unroll
    for (int mi = 0; mi < 4; ++mi)
      af[mi] = *(const f16x8*)&As[(wr * 64 + mi * 16 + (lane & 15)) * 32 +
                                  (lane >> 4) * 8];
#pragma unroll
    for (int ni = 0; ni < 4; ++ni)
      bf[ni] = *(const f16x8*)&Bs[(wc * 64 + ni * 16 + (lane & 15)) * 32 +
                                  (lane >> 4) * 8];
#pragma unroll
    for (int mi = 0; mi < 4; ++mi)
#pragma unroll
      for (int ni = 0; ni < 4; ++ni)
        acc[mi][ni] = __builtin_amdgcn_mfma_f32_16x16x32_f16(
            af[mi], bf[ni], acc[mi][ni], 0, 0, 0);
  }
#undef STG2

  const int cg = lane >> 4, cr = lane & 15;
#pragma unroll
  for (int mi = 0; mi < 4; ++mi) {
#pragma unroll
    for (int ni = 0; ni < 4; ++ni) {
      const int d = d0 + wc * 64 + ni * 16 + cr;
      const int row0 = i0 + wr * 64 + mi * 16 + cg * 4;
#pragma unroll
      for (int r = 0; r < 4; ++r) {
        float v = acc[mi][ni][r];
        size_t o = ((size_t)b * SS + row0 + r) * DF + d;
        outl[o] = v;
        if (writeX) X16n[o] = (_Float16)v;
      }
    }
  }
}

// ---------------------------------------------------------------------------
extern "C" void kernel_launch(void* const* d_in, const int* in_sizes, int n_in,
                              void* d_out, int out_size, void* d_ws,
                              size_t ws_size, hipStream_t stream) {
  const float* X0 = (const float*)d_in[0];
  const int* mask = (const int*)d_in[1];
  const float* W = (const float*)d_in[2];
  const float* Wb = (const float*)d_in[3];
  const float* A = (const float*)d_in[4];
  const float* Ab = (const float*)d_in[5];
  float* out = (float*)d_out;

  const size_t BSD = (size_t)NBATCH * SS * DF;  // 12,582,912 elems
  const size_t BSS = (size_t)NBATCH * SS * SS;  // 16,777,216 elems
  const size_t BS = (size_t)NBATCH * SS;        // 16,384 elems

  char* p = (char*)d_ws;
  _Float16* X16 = (_Float16*)p;   p += BSD * 2;                   // 24 MB
  _Float16* hT16 = (_Float16*)p;  p += BSD * 2;                   // 24 MB
  _Float16* P16 = (_Float16*)p;   p += BSS * 2;                   // 32 MB
  _Float16* W16 = (_Float16*)p;   p += (size_t)2 * DF * DF * 2;   // 2.25 MB
  unsigned char* bmk = (unsigned char*)p; p += BSS / 8;           // 2 MB
  float* psi = (float*)p;  p += 16 * BS * 4;  // 1 MB
  float* psj = (float*)p;  p += 16 * BS * 4;  // 1 MB
  float* pden = (float*)p; p += 64 * BS * 4;  // 4 MB
  float* si = (float*)p;   p += BS * 4;
  float* sjc = (float*)p;  p += BS * 4;
  float* refj = (float*)p; p += BS * 4;
  float* rden = (float*)p; p += BS * 4;

  f32tof16_k<<<12288, 256, 0, stream>>>(X0, X16, (int)BSD);
  f32tof16_k<<<1152, 256, 0, stream>>>(W, W16, 2 * DF * DF);
  pack_k<<<8192, 256, 0, stream>>>(mask, bmk);

  for (int l = 0; l < 2; ++l) {
    gemm1_k<<<dim3(128, 6), 256, 0, stream>>>(X16, W16 + (size_t)l * DF * DF,
                                              Wb + (size_t)l * DF, hT16);
    rowdots2_k<<<dim3(16, 16), 256, 0, stream>>>(hT16, A + (size_t)l * 2 * DF,
                                                 psi, psj);
    rowfin_k<<<16, 256, 0, stream>>>(psi, psj, Ab + l, si, sjc, refj);
    colsum_k<<<dim3(32, 16), 256, 0, stream>>>(bmk, si, sjc, refj, pden);
    colcomb_k<<<64, 256, 0, stream>>>(pden, rden);
    punorm2_k<<<dim3(32, 16), 256, 0, stream>>>(bmk, si, sjc, refj, rden, P16);
    gemm2_k<<<dim3(8, 6, 16), 256, 0, stream>>>(P16, hT16,
                                                out + (size_t)l * BSD, X16,
                                                (l == 0) ? 1 : 0);
  }
}

// Round 8
// 268.098 us; speedup vs baseline: 1.2057x; 1.0665x over previous
//
#include <hip/hip_runtime.h>
#include <cstddef>

#define SS 1024
#define DF 768
#define NBATCH 16
#define GAT_ALPHA 0.2f

typedef _Float16 f16x8 __attribute__((ext_vector_type(8)));
typedef _Float16 f16x4 __attribute__((ext_vector_type(4)));
typedef float f32x4 __attribute__((ext_vector_type(4)));

// async global->LDS, 16B per lane. LDS dest is wave-uniform base + lane*16.
__device__ __forceinline__ void gload16(const void* g, void* l) {
  __builtin_amdgcn_global_load_lds(
      (const __attribute__((address_space(1))) void*)g,
      (__attribute__((address_space(3))) void*)l, 16, 0, 0);
}

__device__ __forceinline__ float lrelu(float t) {
  return fmaxf(t, GAT_ALPHA * t);
}

// ---------------------------------------------------------------------------
// fp32 -> fp16 convert, 4 elems/thread
// ---------------------------------------------------------------------------
__global__ __launch_bounds__(256) void f32tof16_k(const float* __restrict__ in,
                                                  _Float16* __restrict__ out,
                                                  int n) {
  int idx = (blockIdx.x * 256 + threadIdx.x) * 4;
  if (idx + 3 < n) {
    float4 v = *(const float4*)&in[idx];
    f16x4 o;
    o[0] = (_Float16)v.x;
    o[1] = (_Float16)v.y;
    o[2] = (_Float16)v.z;
    o[3] = (_Float16)v.w;
    *(f16x4*)&out[idx] = o;
  }
}

// ---------------------------------------------------------------------------
// pack: int32 mask (64MB) -> bitmask (2MB). byte t holds j=8t..8t+7 (bit k).
// ---------------------------------------------------------------------------
__global__ __launch_bounds__(256) void pack_k(const int* __restrict__ mask,
                                              unsigned char* __restrict__ bm) {
  const size_t t = (size_t)blockIdx.x * 256 + threadIdx.x;  // byte idx, 2M
  const int* mp = mask + t * 8;
  const int4 a = *(const int4*)mp;
  const int4 c = *(const int4*)(mp + 4);
  unsigned v = (unsigned)(a.x > 0) | ((unsigned)(a.y > 0) << 1) |
               ((unsigned)(a.z > 0) << 2) | ((unsigned)(a.w > 0) << 3) |
               ((unsigned)(c.x > 0) << 4) | ((unsigned)(c.y > 0) << 5) |
               ((unsigned)(c.z > 0) << 6) | ((unsigned)(c.w > 0) << 7);
  bm[t] = (unsigned char)v;
}

// ===========================================================================
// 8-wave pipelined GEMM core (both GEMMs):
//  BM=128, BN=384, BK=32; 512 threads; 4-slot LDS ring (32KB/slot = A 8KB +
//  B 24KB); prefetch depth 2 K-tiles; counted vmcnt(4); 2 phases per K-tile;
//  XOR chunk swizzle (chunk ^= (row>>1)&3) with pre-swizzled global source.
//  Wave w owns output cols [w*48, w*48+48) x all 128 rows; acc[8][3] f32x4.
// ===========================================================================

// ---------------------------------------------------------------------------
// GEMM1: hT16[b][n][s] = f16( sum_k X16[m,k]*W16[n,k] + Wb[n] ), m=b*1024+s
// grid 256 blocks: 128 m-tiles x 2 n-tiles (n0 = nt*384)
// ---------------------------------------------------------------------------
__global__ __launch_bounds__(512, 2) void gemm1_k(
    const _Float16* __restrict__ X16, const _Float16* __restrict__ W16,
    const float* __restrict__ Wbl, _Float16* __restrict__ hT16) {
  __shared__ __align__(16) char smem[131072];  // 4 slots x 32KB
  const int flat = blockIdx.x;
  const int swz = (flat & 7) * 32 + (flat >> 3);  // XCD-chunked, 256%8==0
  const int m0 = (swz >> 1) * 128;
  const int n0 = (swz & 1) * 384;
  const int tid = threadIdx.x;
  const int w = tid >> 6, lane = tid & 63;

  // staging: thread covers 16B; row within 128-row round; swizzled src chunk
  const int srow = w * 16 + (lane >> 2);
  const int sk8 = ((lane & 3) ^ ((lane >> 3) & 3)) * 8;  // elems
  // frag read: swizzled 16B-chunk byte offset within 64B row
  const int rby = ((lane >> 4) ^ ((lane >> 1) & 3)) * 16;
  const int rrow = lane & 15;

  f32x4 acc[8][3];
#pragma unroll
  for (int mi = 0; mi < 8; ++mi)
#pragma unroll
    for (int ni = 0; ni < 3; ++ni) acc[mi][ni] = (f32x4)(0.f);

#define STGA1(s, kt)                                                       \
  gload16(&X16[(size_t)(m0 + srow) * DF + (kt) * 32 + sk8],                \
          smem + (s) * 32768 + w * 1024)
#define STGB1(s, kt, q)                                                    \
  gload16(&W16[(size_t)(n0 + (q) * 128 + srow) * DF + (kt) * 32 + sk8],    \
          smem + (s) * 32768 + 8192 + (q) * 8192 + w * 1024)

  const int NT = DF / 32;  // 24
  STGA1(0, 0); STGB1(0, 0, 0); STGB1(0, 0, 1); STGB1(0, 0, 2);
  STGA1(1, 1); STGB1(1, 1, 0); STGB1(1, 1, 1); STGB1(1, 1, 2);
  asm volatile("s_waitcnt vmcnt(4)" ::: "memory");
  asm volatile("s_barrier" ::: "memory");

  for (int t = 0; t < NT; ++t) {
    const int s = t & 3;
    const char* Ab = smem + s * 32768;
    const char* Bb = smem + s * 32768 + 8192;
    // ---- phase A: read B(3) + A(mi 0-3), stage 2, 12 MFMA ----
    f16x8 bfr[3], afr[4];
#pragma unroll
    for (int ni = 0; ni < 3; ++ni)
      bfr[ni] = *(const f16x8*)(Bb + (w * 48 + ni * 16 + rrow) * 64 + rby);
#pragma unroll
    for (int mi = 0; mi < 4; ++mi)
      afr[mi] = *(const f16x8*)(Ab + (mi * 16 + rrow) * 64 + rby);
    if (t + 2 < NT) {
      STGA1((t + 2) & 3, t + 2);
      STGB1((t + 2) & 3, t + 2, 0);
    }
    asm volatile("s_barrier" ::: "memory");
    __builtin_amdgcn_s_setprio(1);
#pragma unroll
    for (int mi = 0; mi < 4; ++mi)
#pragma unroll
      for (int ni = 0; ni < 3; ++ni)
        acc[mi][ni] = __builtin_amdgcn_mfma_f32_16x16x32_f16(
            afr[mi], bfr[ni], acc[mi][ni], 0, 0, 0);
    __builtin_amdgcn_s_setprio(0);
    asm volatile("s_barrier" ::: "memory");
    // ---- phase B: read A(mi 4-7), stage 2, vmcnt, 12 MFMA ----
#pragma unroll
    for (int mi = 0; mi < 4; ++mi)
      afr[mi] = *(const f16x8*)(Ab + ((mi + 4) * 16 + rrow) * 64 + rby);
    if (t + 2 < NT) {
      STGB1((t + 2) & 3, t + 2, 1);
      STGB1((t + 2) & 3, t + 2, 2);
    }
    if (t < NT - 2)
      asm volatile("s_waitcnt vmcnt(4)" ::: "memory");
    else
      asm volatile("s_waitcnt vmcnt(0)" ::: "memory");
    asm volatile("s_barrier" ::: "memory");
    __builtin_amdgcn_s_setprio(1);
#pragma unroll
    for (int mi = 0; mi < 4; ++mi)
#pragma unroll
      for (int ni = 0; ni < 3; ++ni)
        acc[mi + 4][ni] = __builtin_amdgcn_mfma_f32_16x16x32_f16(
            afr[mi], bfr[ni], acc[mi + 4][ni], 0, 0, 0);
    __builtin_amdgcn_s_setprio(0);
    asm volatile("s_barrier" ::: "memory");
  }
#undef STGA1
#undef STGB1

  // epilogue: per-wave LDS transpose (48 cols x 136-pad), coalesced hT write
  _Float16* tb = (_Float16*)smem + (size_t)w * 6528;
  const int cg = lane >> 4, cr = lane & 15;
  float bias[3];
#pragma unroll
  for (int ni = 0; ni < 3; ++ni) bias[ni] = Wbl[n0 + w * 48 + ni * 16 + cr];
#pragma unroll
  for (int mi = 0; mi < 8; ++mi) {
#pragma unroll
    for (int ni = 0; ni < 3; ++ni) {
      f16x4 tv;
#pragma unroll
      for (int r = 0; r < 4; ++r)
        tv[r] = (_Float16)(acc[mi][ni][r] + bias[ni]);
      *(f16x4*)&tb[(ni * 16 + cr) * 136 + mi * 16 + cg * 4] = tv;
    }
  }
  const int bb = m0 >> 10, s0 = m0 & 1023;
#pragma unroll
  for (int pass = 0; pass < 12; ++pass) {
    const int c = pass * 4 + (lane >> 4);
    f16x8 v = *(const f16x8*)&tb[c * 136 + (lane & 15) * 8];
    *(f16x8*)&hT16[((size_t)bb * DF + n0 + w * 48 + c) * SS + s0 +
                   (lane & 15) * 8] = v;
  }
}

// ---------------------------------------------------------------------------
// GEMM2: out[b,i,d] = sum_j P16[b,i,j] * hT16[b,d,j]   (K=1024)
// grid 256 blocks: b(16) x i-tile(8, 128) x d-tile(2, 384)
// ---------------------------------------------------------------------------
__global__ __launch_bounds__(512, 2) void gemm2_k(
    const _Float16* __restrict__ P16, const _Float16* __restrict__ hT16,
    float* __restrict__ outl, _Float16* __restrict__ X16n, int writeX) {
  __shared__ __align__(16) char smem[131072];
  const int flat = blockIdx.x;
  const int swz = (flat & 7) * 32 + (flat >> 3);  // XCD gets 2 batches
  const int b = swz >> 4;
  const int i0 = ((swz >> 1) & 7) * 128;
  const int d0 = (swz & 1) * 384;
  const int tid = threadIdx.x;
  const int w = tid >> 6, lane = tid & 63;

  const int srow = w * 16 + (lane >> 2);
  const int sk8 = ((lane & 3) ^ ((lane >> 3) & 3)) * 8;
  const int rby = ((lane >> 4) ^ ((lane >> 1) & 3)) * 16;
  const int rrow = lane & 15;

  const _Float16* Pb = P16 + ((size_t)b << 20);
  const _Float16* hTb = hT16 + (size_t)b * DF * SS;

  f32x4 acc[8][3];
#pragma unroll
  for (int mi = 0; mi < 8; ++mi)
#pragma unroll
    for (int ni = 0; ni < 3; ++ni) acc[mi][ni] = (f32x4)(0.f);

#define STGA2(s, kt)                                                       \
  gload16(&Pb[((size_t)(i0 + srow) << 10) + (kt) * 32 + sk8],              \
          smem + (s) * 32768 + w * 1024)
#define STGB2(s, kt, q)                                                    \
  gload16(&hTb[((size_t)(d0 + (q) * 128 + srow)) * SS + (kt) * 32 + sk8],  \
          smem + (s) * 32768 + 8192 + (q) * 8192 + w * 1024)

  const int NT = SS / 32;  // 32
  STGA2(0, 0); STGB2(0, 0, 0); STGB2(0, 0, 1); STGB2(0, 0, 2);
  STGA2(1, 1); STGB2(1, 1, 0); STGB2(1, 1, 1); STGB2(1, 1, 2);
  asm volatile("s_waitcnt vmcnt(4)" ::: "memory");
  asm volatile("s_barrier" ::: "memory");

  for (int t = 0; t < NT; ++t) {
    const int s = t & 3;
    const char* Ab = smem + s * 32768;
    const char* Bb = smem + s * 32768 + 8192;
    f16x8 bfr[3], afr[4];
#pragma unroll
    for (int ni = 0; ni < 3; ++ni)
      bfr[ni] = *(const f16x8*)(Bb + (w * 48 + ni * 16 + rrow) * 64 + rby);
#pragma unroll
    for (int mi = 0; mi < 4; ++mi)
      afr[mi] = *(const f16x8*)(Ab + (mi * 16 + rrow) * 64 + rby);
    if (t + 2 < NT) {
      STGA2((t + 2) & 3, t + 2);
      STGB2((t + 2) & 3, t + 2, 0);
    }
    asm volatile("s_barrier" ::: "memory");
    __builtin_amdgcn_s_setprio(1);
#pragma unroll
    for (int mi = 0; mi < 4; ++mi)
#pragma unroll
      for (int ni = 0; ni < 3; ++ni)
        acc[mi][ni] = __builtin_amdgcn_mfma_f32_16x16x32_f16(
            afr[mi], bfr[ni], acc[mi][ni], 0, 0, 0);
    __builtin_amdgcn_s_setprio(0);
    asm volatile("s_barrier" ::: "memory");
#pragma unroll
    for (int mi = 0; mi < 4; ++mi)
      afr[mi] = *(const f16x8*)(Ab + ((mi + 4) * 16 + rrow) * 64 + rby);
    if (t + 2 < NT) {
      STGB2((t + 2) & 3, t + 2, 1);
      STGB2((t + 2) & 3, t + 2, 2);
    }
    if (t < NT - 2)
      asm volatile("s_waitcnt vmcnt(4)" ::: "memory");
    else
      asm volatile("s_waitcnt vmcnt(0)" ::: "memory");
    asm volatile("s_barrier" ::: "memory");
    __builtin_amdgcn_s_setprio(1);
#pragma unroll
    for (int mi = 0; mi < 4; ++mi)
#pragma unroll
      for (int ni = 0; ni < 3; ++ni)
        acc[mi + 4][ni] = __builtin_amdgcn_mfma_f32_16x16x32_f16(
            afr[mi], bfr[ni], acc[mi + 4][ni], 0, 0, 0);
    __builtin_amdgcn_s_setprio(0);
    asm volatile("s_barrier" ::: "memory");
  }
#undef STGA2
#undef STGB2

  const int cg = lane >> 4, cr = lane & 15;
#pragma unroll
  for (int mi = 0; mi < 8; ++mi) {
#pragma unroll
    for (int ni = 0; ni < 3; ++ni) {
      const int d = d0 + w * 48 + ni * 16 + cr;
      const int row0 = i0 + mi * 16 + cg * 4;
#pragma unroll
      for (int r = 0; r < 4; ++r) {
        float v = acc[mi][ni][r];
        size_t o = ((size_t)b * SS + row0 + r) * DF + d;
        outl[o] = v;
        if (writeX) X16n[o] = (_Float16)v;
      }
    }
  }
}

// ---------------------------------------------------------------------------
// rowdots2: si/sj partials from hT16 (coalesced), combined by rowfin.
// ---------------------------------------------------------------------------
__global__ __launch_bounds__(256) void rowdots2_k(
    const _Float16* __restrict__ hT, const float* __restrict__ Al,
    float* __restrict__ psi, float* __restrict__ psj) {
  const int dc = blockIdx.x;  // 0..15 (48 d's each)
  const int b = blockIdx.y;   // 0..15
  const int t = threadIdx.x;
  const int s4 = t * 4;
  __shared__ float sa[48], sd[48];
  if (t < 48) {
    sa[t] = Al[dc * 48 + t];
    sd[t] = Al[DF + dc * 48 + t];
  }
  __syncthreads();
  float as[4] = {0.f, 0.f, 0.f, 0.f}, ad[4] = {0.f, 0.f, 0.f, 0.f};
  const _Float16* hp = hT + ((size_t)b * DF + dc * 48) * SS + s4;
#pragma unroll 4
  for (int q = 0; q < 48; ++q) {
    const f16x4 hv = *(const f16x4*)(hp + (size_t)q * SS);
    const float ws = sa[q], wd = sd[q];
#pragma unroll
    for (int r = 0; r < 4; ++r) {
      const float hf = (float)hv[r];
      as[r] = fmaf(hf, ws, as[r]);
      ad[r] = fmaf(hf, wd, ad[r]);
    }
  }
  const size_t o = (size_t)dc * 16384 + (b << 10) + s4;
  *(float4*)&psi[o] = *(float4*)as;
  *(float4*)&psj[o] = *(float4*)ad;
}

// ---------------------------------------------------------------------------
// rowfin: combine psi/psj chunks -> si; per-batch max(si); sjc/refj.
// ---------------------------------------------------------------------------
__global__ __launch_bounds__(256) void rowfin_k(const float* __restrict__ psi,
                                                const float* __restrict__ psj,
                                                const float* __restrict__ Abp,
                                                float* __restrict__ si,
                                                float* __restrict__ sjc,
                                                float* __restrict__ refj) {
  const int b = blockIdx.x;
  const int t = threadIdx.x;
  __shared__ float red[256];
  float siv[4], sjv[4];
  float mloc = -1e30f;
#pragma unroll
  for (int q = 0; q < 4; ++q) {
    const int idx = (b << 10) + t + (q << 8);
    float a = 0.f, d = 0.f;
#pragma unroll
    for (int c = 0; c < 16; ++c) {
      a += psi[(size_t)c * 16384 + idx];
      d += psj[(size_t)c * 16384 + idx];
    }
    siv[q] = a;
    sjv[q] = d;
    si[idx] = a;
    mloc = fmaxf(mloc, a);
  }
  red[t] = mloc;
  __syncthreads();
  for (int off = 128; off > 0; off >>= 1) {
    if (t < off) red[t] = fmaxf(red[t], red[t + off]);
    __syncthreads();
  }
  const float maxsi = red[0];
  const float ab = Abp[0];
#pragma unroll
  for (int q = 0; q < 4; ++q) {
    const int idx = (b << 10) + t + (q << 8);
    const float c = sjv[q] + ab;
    sjc[idx] = c;
    refj[idx] = lrelu(maxsi + c);
  }
}

// ---------------------------------------------------------------------------
// colsum: column partial sums of exp(lrelu(si+sjc)-refj) over masked i.
// ---------------------------------------------------------------------------
__global__ __launch_bounds__(256) void colsum_k(
    const unsigned char* __restrict__ bm, const float* __restrict__ si,
    const float* __restrict__ sjc, const float* __restrict__ refj,
    float* __restrict__ pden) {
  const int g = blockIdx.x;  // 0..31
  const int b = blockIdx.y;  // 0..15
  const int t = threadIdx.x;
  const int jb = t & 127;
  const int half = t >> 7;
  const int row0 = (g << 5) + (half << 4);
  __shared__ float s_si[32];
  if (t < 32) s_si[t] = si[(b << 10) + (g << 5) + t];
  __syncthreads();
  float sc[8], rf[8];
  *(float4*)&sc[0] = *(const float4*)&sjc[(b << 10) + jb * 8];
  *(float4*)&sc[4] = *(const float4*)&sjc[(b << 10) + jb * 8 + 4];
  *(float4*)&rf[0] = *(const float4*)&refj[(b << 10) + jb * 8];
  *(float4*)&rf[4] = *(const float4*)&refj[(b << 10) + jb * 8 + 4];
  float den[8] = {0.f, 0.f, 0.f, 0.f, 0.f, 0.f, 0.f, 0.f};
  const unsigned char* bp = bm + ((size_t)b << 17) + ((size_t)row0 << 7) + jb;
#pragma unroll 4
  for (int r = 0; r < 16; ++r) {
    const unsigned m = bp[(size_t)r << 7];
    const float siv = s_si[(half << 4) + r];
#pragma unroll
    for (int k = 0; k < 8; ++k) {
      if ((m >> k) & 1) den[k] += __expf(lrelu(siv + sc[k]) - rf[k]);
    }
  }
  const size_t o = ((size_t)(g * 2 + half)) * 16384 + (b << 10) + jb * 8;
  *(float4*)&pden[o] = *(float4*)&den[0];
  *(float4*)&pden[o + 4] = *(float4*)&den[4];
}

// combine 64 chunks -> rden (sentinel -1 for fully-masked column)
__global__ __launch_bounds__(256) void colcomb_k(const float* __restrict__ pden,
                                                 float* __restrict__ rden) {
  const int idx = blockIdx.x * 256 + threadIdx.x;  // b*1024 + j
  float s = 0.f;
#pragma unroll
  for (int c = 0; c < 64; ++c) s += pden[(size_t)c * 16384 + idx];
  rden[idx] = (s > 0.f) ? 1.f / s : -1.f;
}

// ---------------------------------------------------------------------------
// punorm2: P16[b][i][j] = normalized attention weight (f16), single bitmask
// pass. rden<0 sentinel => uniform column 1/S (reference's all-masked case).
// ---------------------------------------------------------------------------
__global__ __launch_bounds__(256) void punorm2_k(
    const unsigned char* __restrict__ bm, const float* __restrict__ si,
    const float* __restrict__ sjc, const float* __restrict__ refj,
    const float* __restrict__ rden, _Float16* __restrict__ P16) {
  const int g = blockIdx.x;  // 0..31
  const int b = blockIdx.y;  // 0..15
  const int t = threadIdx.x;
  const int jb = t & 127;
  const int half = t >> 7;
  const int row0 = (g << 5) + (half << 4);
  __shared__ float s_si[32];
  if (t < 32) s_si[t] = si[(b << 10) + (g << 5) + t];
  __syncthreads();
  float sc[8], rf[8], rd[8];
  *(float4*)&sc[0] = *(const float4*)&sjc[(b << 10) + jb * 8];
  *(float4*)&sc[4] = *(const float4*)&sjc[(b << 10) + jb * 8 + 4];
  *(float4*)&rf[0] = *(const float4*)&refj[(b << 10) + jb * 8];
  *(float4*)&rf[4] = *(const float4*)&refj[(b << 10) + jb * 8 + 4];
  *(float4*)&rd[0] = *(const float4*)&rden[(b << 10) + jb * 8];
  *(float4*)&rd[4] = *(const float4*)&rden[(b << 10) + jb * 8 + 4];
  const unsigned char* bp = bm + ((size_t)b << 17) + ((size_t)row0 << 7) + jb;
  _Float16* pp = P16 + ((size_t)b << 20) + ((size_t)row0 << 10) + jb * 8;
#pragma unroll 4
  for (int r = 0; r < 16; ++r) {
    const unsigned m = bp[(size_t)r << 7];
    const float siv = s_si[(half << 4) + r];
    f16x8 ph;
#pragma unroll
    for (int k = 0; k < 8; ++k) {
      float p;
      if (rd[k] < 0.f)
        p = 0.0009765625f;  // 1/1024 uniform (all-masked column)
      else if ((m >> k) & 1)
        p = __expf(lrelu(siv + sc[k]) - rf[k]) * rd[k];
      else
        p = 0.f;
      ph[k] = (_Float16)p;
    }
    *(f16x8*)(pp + ((size_t)r << 10)) = ph;
  }
}

// ---------------------------------------------------------------------------
extern "C" void kernel_launch(void* const* d_in, const int* in_sizes, int n_in,
                              void* d_out, int out_size, void* d_ws,
                              size_t ws_size, hipStream_t stream) {
  const float* X0 = (const float*)d_in[0];
  const int* mask = (const int*)d_in[1];
  const float* W = (const float*)d_in[2];
  const float* Wb = (const float*)d_in[3];
  const float* A = (const float*)d_in[4];
  const float* Ab = (const float*)d_in[5];
  float* out = (float*)d_out;

  const size_t BSD = (size_t)NBATCH * SS * DF;  // 12,582,912 elems
  const size_t BSS = (size_t)NBATCH * SS * SS;  // 16,777,216 elems
  const size_t BS = (size_t)NBATCH * SS;        // 16,384 elems

  char* p = (char*)d_ws;
  _Float16* X16 = (_Float16*)p;   p += BSD * 2;                   // 24 MB
  _Float16* hT16 = (_Float16*)p;  p += BSD * 2;                   // 24 MB
  _Float16* P16 = (_Float16*)p;   p += BSS * 2;                   // 32 MB
  _Float16* W16 = (_Float16*)p;   p += (size_t)2 * DF * DF * 2;   // 2.25 MB
  unsigned char* bmk = (unsigned char*)p; p += BSS / 8;           // 2 MB
  float* psi = (float*)p;  p += 16 * BS * 4;  // 1 MB
  float* psj = (float*)p;  p += 16 * BS * 4;  // 1 MB
  float* pden = (float*)p; p += 64 * BS * 4;  // 4 MB
  float* si = (float*)p;   p += BS * 4;
  float* sjc = (float*)p;  p += BS * 4;
  float* refj = (float*)p; p += BS * 4;
  float* rden = (float*)p; p += BS * 4;

  f32tof16_k<<<12288, 256, 0, stream>>>(X0, X16, (int)BSD);
  f32tof16_k<<<1152, 256, 0, stream>>>(W, W16, 2 * DF * DF);
  pack_k<<<8192, 256, 0, stream>>>(mask, bmk);

  for (int l = 0; l < 2; ++l) {
    gemm1_k<<<256, 512, 0, stream>>>(X16, W16 + (size_t)l * DF * DF,
                                     Wb + (size_t)l * DF, hT16);
    rowdots2_k<<<dim3(16, 16), 256, 0, stream>>>(hT16, A + (size_t)l * 2 * DF,
                                                 psi, psj);
    rowfin_k<<<16, 256, 0, stream>>>(psi, psj, Ab + l, si, sjc, refj);
    colsum_k<<<dim3(32, 16), 256, 0, stream>>>(bmk, si, sjc, refj, pden);
    colcomb_k<<<64, 256, 0, stream>>>(pden, rden);
    punorm2_k<<<dim3(32, 16), 256, 0, stream>>>(bmk, si, sjc, refj, rden, P16);
    gemm2_k<<<256, 512, 0, stream>>>(P16, hT16, out + (size_t)l * BSD, X16,
                                     (l == 0) ? 1 : 0);
  }
}

// Round 9
// 255.036 us; speedup vs baseline: 1.2675x; 1.0512x over previous
//
#include <hip/hip_runtime.h>
#include <cstddef>

#define SS 1024
#define DF 768
#define NBATCH 16
#define GAT_ALPHA 0.2f

typedef _Float16 f16x8 __attribute__((ext_vector_type(8)));
typedef _Float16 f16x4 __attribute__((ext_vector_type(4)));
typedef float f32x4 __attribute__((ext_vector_type(4)));

// async global->LDS, 16B per lane. LDS dest is wave-uniform base + lane*16.
__device__ __forceinline__ void gload16(const void* g, void* l) {
  __builtin_amdgcn_global_load_lds(
      (const __attribute__((address_space(1))) void*)g,
      (__attribute__((address_space(3))) void*)l, 16, 0, 0);
}

__device__ __forceinline__ float lrelu(float t) {
  return fmaxf(t, GAT_ALPHA * t);
}

// ---------------------------------------------------------------------------
// fp32 -> fp16 convert, 4 elems/thread
// ---------------------------------------------------------------------------
__global__ __launch_bounds__(256) void f32tof16_k(const float* __restrict__ in,
                                                  _Float16* __restrict__ out,
                                                  int n) {
  int idx = (blockIdx.x * 256 + threadIdx.x) * 4;
  if (idx + 3 < n) {
    float4 v = *(const float4*)&in[idx];
    f16x4 o;
    o[0] = (_Float16)v.x;
    o[1] = (_Float16)v.y;
    o[2] = (_Float16)v.z;
    o[3] = (_Float16)v.w;
    *(f16x4*)&out[idx] = o;
  }
}

// ---------------------------------------------------------------------------
// pack: int32 mask (64MB) -> bitmask (2MB). byte t holds j=8t..8t+7 (bit k).
// ---------------------------------------------------------------------------
__global__ __launch_bounds__(256) void pack_k(const int* __restrict__ mask,
                                              unsigned char* __restrict__ bm) {
  const size_t t = (size_t)blockIdx.x * 256 + threadIdx.x;  // byte idx, 2M
  const int* mp = mask + t * 8;
  const int4 a = *(const int4*)mp;
  const int4 c = *(const int4*)(mp + 4);
  unsigned v = (unsigned)(a.x > 0) | ((unsigned)(a.y > 0) << 1) |
               ((unsigned)(a.z > 0) << 2) | ((unsigned)(a.w > 0) << 3) |
               ((unsigned)(c.x > 0) << 4) | ((unsigned)(c.y > 0) << 5) |
               ((unsigned)(c.z > 0) << 6) | ((unsigned)(c.w > 0) << 7);
  bm[t] = (unsigned char)v;
}

// ===========================================================================
// 8-wave pipelined GEMM core: BM=128, BN=384, BK=32; 512 threads; 4-slot LDS
// ring (32KB/slot); depth-2 prefetch; counted vmcnt(4); ONE barrier per
// K-tile: {11 ds_read | 4 gload_lds | vmcnt | barrier | 24 MFMA}.
// Safety: reads slot t, writes slot t+2 (disjoint); slot t+2's prior readers
// finished 2 barriers ago; vmcnt(4)+barrier@t-1 guarantees slot-t loads of
// ALL waves landed before window t's ds_reads. Max wave skew = 1 window.
// ===========================================================================

// ---------------------------------------------------------------------------
// GEMM1: hT16[b][n][s] = f16( sum_k X16[m,k]*W16[n,k] + Wb[n] ), m=b*1024+s
// Epilogue: LDS transpose -> coalesced hT write + fused rowdots partials
// (psi2/psj2[nt][m], nt=n-tile 0/1) for si/sj.
// ---------------------------------------------------------------------------
__global__ __launch_bounds__(512, 2) void gemm1_k(
    const _Float16* __restrict__ X16, const _Float16* __restrict__ W16,
    const float* __restrict__ Wbl, const float* __restrict__ Al,
    _Float16* __restrict__ hT16, float* __restrict__ psi2,
    float* __restrict__ psj2) {
  __shared__ __align__(16) char smem[131072];  // 4 slots x 32KB
  const int flat = blockIdx.x;
  const int swz = (flat & 7) * 32 + (flat >> 3);  // XCD-chunked, 256%8==0
  const int m0 = (swz >> 1) * 128;
  const int n0 = (swz & 1) * 384;
  const int tid = threadIdx.x;
  const int w = tid >> 6, lane = tid & 63;

  const int srow = w * 16 + (lane >> 2);
  const int sk8 = ((lane & 3) ^ ((lane >> 3) & 3)) * 8;  // swizzled src chunk
  const int rby = ((lane >> 4) ^ ((lane >> 1) & 3)) * 16;  // swizzled read
  const int rrow = lane & 15;

  f32x4 acc[8][3];
#pragma unroll
  for (int mi = 0; mi < 8; ++mi)
#pragma unroll
    for (int ni = 0; ni < 3; ++ni) acc[mi][ni] = (f32x4)(0.f);

#define STGA1(s, kt)                                                       \
  gload16(&X16[(size_t)(m0 + srow) * DF + (kt) * 32 + sk8],                \
          smem + (s) * 32768 + w * 1024)
#define STGB1(s, kt, q)                                                    \
  gload16(&W16[(size_t)(n0 + (q) * 128 + srow) * DF + (kt) * 32 + sk8],    \
          smem + (s) * 32768 + 8192 + (q) * 8192 + w * 1024)

  const int NT = DF / 32;  // 24
  STGA1(0, 0); STGB1(0, 0, 0); STGB1(0, 0, 1); STGB1(0, 0, 2);
  STGA1(1, 1); STGB1(1, 1, 0); STGB1(1, 1, 1); STGB1(1, 1, 2);
  asm volatile("s_waitcnt vmcnt(4)" ::: "memory");
  asm volatile("s_barrier" ::: "memory");

  for (int t = 0; t < NT; ++t) {
    const int s = t & 3;
    const char* Ab = smem + s * 32768;
    const char* Bb = smem + s * 32768 + 8192;
    f16x8 bfr[3], afr[8];
#pragma unroll
    for (int ni = 0; ni < 3; ++ni)
      bfr[ni] = *(const f16x8*)(Bb + (w * 48 + ni * 16 + rrow) * 64 + rby);
#pragma unroll
    for (int mi = 0; mi < 8; ++mi)
      afr[mi] = *(const f16x8*)(Ab + (mi * 16 + rrow) * 64 + rby);
    if (t + 2 < NT) {
      const int s2 = (t + 2) & 3;
      STGA1(s2, t + 2);
      STGB1(s2, t + 2, 0);
      STGB1(s2, t + 2, 1);
      STGB1(s2, t + 2, 2);
    }
    if (t < NT - 2)
      asm volatile("s_waitcnt vmcnt(4)" ::: "memory");
    else
      asm volatile("s_waitcnt vmcnt(0)" ::: "memory");
    asm volatile("s_barrier" ::: "memory");
    __builtin_amdgcn_s_setprio(1);
#pragma unroll
    for (int mi = 0; mi < 8; ++mi)
#pragma unroll
      for (int ni = 0; ni < 3; ++ni)
        acc[mi][ni] = __builtin_amdgcn_mfma_f32_16x16x32_f16(
            afr[mi], bfr[ni], acc[mi][ni], 0, 0, 0);
    __builtin_amdgcn_s_setprio(0);
  }
#undef STGA1
#undef STGB1

  // ---- epilogue ----
  __syncthreads();  // waitcnt(0)+barrier: all in-flight LDS ops retired

  // LDS regions (reusing slot memory, now safe):
  _Float16* tb = (_Float16*)smem + (size_t)w * 6528;  // per-wave 48x136
  float* asrc = (float*)(smem + 104448);              // 384 f
  float* adst = asrc + 384;                           // 384 f
  float* pwsi = adst + 384;                           // 8x128 f
  float* pwsj = pwsi + 1024;                          // 8x128 f

  for (int i = tid; i < 384; i += 512) {
    asrc[i] = Al[n0 + i];
    adst[i] = Al[DF + n0 + i];
  }
  const int cg = lane >> 4, cr = lane & 15;
  float bias[3];
#pragma unroll
  for (int ni = 0; ni < 3; ++ni) bias[ni] = Wbl[n0 + w * 48 + ni * 16 + cr];
#pragma unroll
  for (int mi = 0; mi < 8; ++mi) {
#pragma unroll
    for (int ni = 0; ni < 3; ++ni) {
      f16x4 tv;
#pragma unroll
      for (int r = 0; r < 4; ++r)
        tv[r] = (_Float16)(acc[mi][ni][r] + bias[ni]);
      *(f16x4*)&tb[(ni * 16 + cr) * 136 + mi * 16 + cg * 4] = tv;
    }
  }
  __syncthreads();

  // fused rowdots: per-wave column-dot over its 48 cols, 2 rows/lane
  const float* wa = asrc + w * 48;
  const float* wdp = adst + w * 48;
#pragma unroll
  for (int rr = 0; rr < 2; ++rr) {
    const int r = lane + rr * 64;
    float ps = 0.f, pd = 0.f;
#pragma unroll 8
    for (int c = 0; c < 48; ++c) {
      const float hv = (float)tb[c * 136 + r];
      ps = fmaf(hv, wa[c], ps);
      pd = fmaf(hv, wdp[c], pd);
    }
    pwsi[w * 128 + r] = ps;
    pwsj[w * 128 + r] = pd;
  }
  __syncthreads();
  if (tid < 128) {
    float s = 0.f, d2 = 0.f;
#pragma unroll
    for (int ww = 0; ww < 8; ++ww) {
      s += pwsi[ww * 128 + tid];
      d2 += pwsj[ww * 128 + tid];
    }
    const int nt = swz & 1;
    psi2[nt * 16384 + m0 + tid] = s;
    psj2[nt * 16384 + m0 + tid] = d2;
  }

  // coalesced hT write from own tb region
  const int bb = m0 >> 10, s0 = m0 & 1023;
#pragma unroll
  for (int pass = 0; pass < 12; ++pass) {
    const int c = pass * 4 + (lane >> 4);
    f16x8 v = *(const f16x8*)&tb[c * 136 + (lane & 15) * 8];
    *(f16x8*)&hT16[((size_t)bb * DF + n0 + w * 48 + c) * SS + s0 +
                   (lane & 15) * 8] = v;
  }
}

// ---------------------------------------------------------------------------
// GEMM2: out[b,i,d] = sum_j P16[b,i,j] * hT16[b,d,j]   (K=1024)
// ---------------------------------------------------------------------------
__global__ __launch_bounds__(512, 2) void gemm2_k(
    const _Float16* __restrict__ P16, const _Float16* __restrict__ hT16,
    float* __restrict__ outl, _Float16* __restrict__ X16n, int writeX) {
  __shared__ __align__(16) char smem[131072];
  const int flat = blockIdx.x;
  const int swz = (flat & 7) * 32 + (flat >> 3);  // XCD gets 2 batches
  const int b = swz >> 4;
  const int i0 = ((swz >> 1) & 7) * 128;
  const int d0 = (swz & 1) * 384;
  const int tid = threadIdx.x;
  const int w = tid >> 6, lane = tid & 63;

  const int srow = w * 16 + (lane >> 2);
  const int sk8 = ((lane & 3) ^ ((lane >> 3) & 3)) * 8;
  const int rby = ((lane >> 4) ^ ((lane >> 1) & 3)) * 16;
  const int rrow = lane & 15;

  const _Float16* Pb = P16 + ((size_t)b << 20);
  const _Float16* hTb = hT16 + (size_t)b * DF * SS;

  f32x4 acc[8][3];
#pragma unroll
  for (int mi = 0; mi < 8; ++mi)
#pragma unroll
    for (int ni = 0; ni < 3; ++ni) acc[mi][ni] = (f32x4)(0.f);

#define STGA2(s, kt)                                                       \
  gload16(&Pb[((size_t)(i0 + srow) << 10) + (kt) * 32 + sk8],              \
          smem + (s) * 32768 + w * 1024)
#define STGB2(s, kt, q)                                                    \
  gload16(&hTb[((size_t)(d0 + (q) * 128 + srow)) * SS + (kt) * 32 + sk8],  \
          smem + (s) * 32768 + 8192 + (q) * 8192 + w * 1024)

  const int NT = SS / 32;  // 32
  STGA2(0, 0); STGB2(0, 0, 0); STGB2(0, 0, 1); STGB2(0, 0, 2);
  STGA2(1, 1); STGB2(1, 1, 0); STGB2(1, 1, 1); STGB2(1, 1, 2);
  asm volatile("s_waitcnt vmcnt(4)" ::: "memory");
  asm volatile("s_barrier" ::: "memory");

  for (int t = 0; t < NT; ++t) {
    const int s = t & 3;
    const char* Ab = smem + s * 32768;
    const char* Bb = smem + s * 32768 + 8192;
    f16x8 bfr[3], afr[8];
#pragma unroll
    for (int ni = 0; ni < 3; ++ni)
      bfr[ni] = *(const f16x8*)(Bb + (w * 48 + ni * 16 + rrow) * 64 + rby);
#pragma unroll
    for (int mi = 0; mi < 8; ++mi)
      afr[mi] = *(const f16x8*)(Ab + (mi * 16 + rrow) * 64 + rby);
    if (t + 2 < NT) {
      const int s2 = (t + 2) & 3;
      STGA2(s2, t + 2);
      STGB2(s2, t + 2, 0);
      STGB2(s2, t + 2, 1);
      STGB2(s2, t + 2, 2);
    }
    if (t < NT - 2)
      asm volatile("s_waitcnt vmcnt(4)" ::: "memory");
    else
      asm volatile("s_waitcnt vmcnt(0)" ::: "memory");
    asm volatile("s_barrier" ::: "memory");
    __builtin_amdgcn_s_setprio(1);
#pragma unroll
    for (int mi = 0; mi < 8; ++mi)
#pragma unroll
      for (int ni = 0; ni < 3; ++ni)
        acc[mi][ni] = __builtin_amdgcn_mfma_f32_16x16x32_f16(
            afr[mi], bfr[ni], acc[mi][ni], 0, 0, 0);
    __builtin_amdgcn_s_setprio(0);
  }
#undef STGA2
#undef STGB2

  const int cg = lane >> 4, cr = lane & 15;
#pragma unroll
  for (int mi = 0; mi < 8; ++mi) {
#pragma unroll
    for (int ni = 0; ni < 3; ++ni) {
      const int d = d0 + w * 48 + ni * 16 + cr;
      const int row0 = i0 + mi * 16 + cg * 4;
#pragma unroll
      for (int r = 0; r < 4; ++r) {
        float v = acc[mi][ni][r];
        size_t o = ((size_t)b * SS + row0 + r) * DF + d;
        outl[o] = v;
        if (writeX) X16n[o] = (_Float16)v;
      }
    }
  }
}

// ---------------------------------------------------------------------------
// rowfin: combine 2 n-tile partials -> si; per-batch max(si); sjc/refj.
// ---------------------------------------------------------------------------
__global__ __launch_bounds__(256) void rowfin_k(const float* __restrict__ psi2,
                                                const float* __restrict__ psj2,
                                                const float* __restrict__ Abp,
                                                float* __restrict__ si,
                                                float* __restrict__ sjc,
                                                float* __restrict__ refj) {
  const int b = blockIdx.x;
  const int t = threadIdx.x;
  __shared__ float red[256];
  float siv[4], sjv[4];
  float mloc = -1e30f;
#pragma unroll
  for (int q = 0; q < 4; ++q) {
    const int idx = (b << 10) + t + (q << 8);
    const float a = psi2[idx] + psi2[16384 + idx];
    const float d = psj2[idx] + psj2[16384 + idx];
    siv[q] = a;
    sjv[q] = d;
    si[idx] = a;
    mloc = fmaxf(mloc, a);
  }
  red[t] = mloc;
  __syncthreads();
  for (int off = 128; off > 0; off >>= 1) {
    if (t < off) red[t] = fmaxf(red[t], red[t + off]);
    __syncthreads();
  }
  const float maxsi = red[0];
  const float ab = Abp[0];
#pragma unroll
  for (int q = 0; q < 4; ++q) {
    const int idx = (b << 10) + t + (q << 8);
    const float c = sjv[q] + ab;
    sjc[idx] = c;
    refj[idx] = lrelu(maxsi + c);
  }
}

// ---------------------------------------------------------------------------
// colsum: column partial sums of exp(lrelu(si+sjc)-refj) over masked i.
// ---------------------------------------------------------------------------
__global__ __launch_bounds__(256) void colsum_k(
    const unsigned char* __restrict__ bm, const float* __restrict__ si,
    const float* __restrict__ sjc, const float* __restrict__ refj,
    float* __restrict__ pden) {
  const int g = blockIdx.x;  // 0..31
  const int b = blockIdx.y;  // 0..15
  const int t = threadIdx.x;
  const int jb = t & 127;
  const int half = t >> 7;
  const int row0 = (g << 5) + (half << 4);
  __shared__ float s_si[32];
  if (t < 32) s_si[t] = si[(b << 10) + (g << 5) + t];
  __syncthreads();
  float sc[8], rf[8];
  *(float4*)&sc[0] = *(const float4*)&sjc[(b << 10) + jb * 8];
  *(float4*)&sc[4] = *(const float4*)&sjc[(b << 10) + jb * 8 + 4];
  *(float4*)&rf[0] = *(const float4*)&refj[(b << 10) + jb * 8];
  *(float4*)&rf[4] = *(const float4*)&refj[(b << 10) + jb * 8 + 4];
  float den[8] = {0.f, 0.f, 0.f, 0.f, 0.f, 0.f, 0.f, 0.f};
  const unsigned char* bp = bm + ((size_t)b << 17) + ((size_t)row0 << 7) + jb;
#pragma unroll 4
  for (int r = 0; r < 16; ++r) {
    const unsigned m = bp[(size_t)r << 7];
    const float siv = s_si[(half << 4) + r];
#pragma unroll
    for (int k = 0; k < 8; ++k) {
      if ((m >> k) & 1) den[k] += __expf(lrelu(siv + sc[k]) - rf[k]);
    }
  }
  const size_t o = ((size_t)(g * 2 + half)) * 16384 + (b << 10) + jb * 8;
  *(float4*)&pden[o] = *(float4*)&den[0];
  *(float4*)&pden[o + 4] = *(float4*)&den[4];
}

// combine 64 chunks -> rden (sentinel -1 for fully-masked column)
__global__ __launch_bounds__(256) void colcomb_k(const float* __restrict__ pden,
                                                 float* __restrict__ rden) {
  const int idx = blockIdx.x * 256 + threadIdx.x;  // b*1024 + j
  float s = 0.f;
#pragma unroll
  for (int c = 0; c < 64; ++c) s += pden[(size_t)c * 16384 + idx];
  rden[idx] = (s > 0.f) ? 1.f / s : -1.f;
}

// ---------------------------------------------------------------------------
// punorm2: P16[b][i][j] = normalized attention weight (f16), single bitmask
// pass. rden<0 sentinel => uniform column 1/S (reference's all-masked case).
// ---------------------------------------------------------------------------
__global__ __launch_bounds__(256) void punorm2_k(
    const unsigned char* __restrict__ bm, const float* __restrict__ si,
    const float* __restrict__ sjc, const float* __restrict__ refj,
    const float* __restrict__ rden, _Float16* __restrict__ P16) {
  const int g = blockIdx.x;  // 0..31
  const int b = blockIdx.y;  // 0..15
  const int t = threadIdx.x;
  const int jb = t & 127;
  const int half = t >> 7;
  const int row0 = (g << 5) + (half << 4);
  __shared__ float s_si[32];
  if (t < 32) s_si[t] = si[(b << 10) + (g << 5) + t];
  __syncthreads();
  float sc[8], rf[8], rd[8];
  *(float4*)&sc[0] = *(const float4*)&sjc[(b << 10) + jb * 8];
  *(float4*)&sc[4] = *(const float4*)&sjc[(b << 10) + jb * 8 + 4];
  *(float4*)&rf[0] = *(const float4*)&refj[(b << 10) + jb * 8];
  *(float4*)&rf[4] = *(const float4*)&refj[(b << 10) + jb * 8 + 4];
  *(float4*)&rd[0] = *(const float4*)&rden[(b << 10) + jb * 8];
  *(float4*)&rd[4] = *(const float4*)&rden[(b << 10) + jb * 8 + 4];
  const unsigned char* bp = bm + ((size_t)b << 17) + ((size_t)row0 << 7) + jb;
  _Float16* pp = P16 + ((size_t)b << 20) + ((size_t)row0 << 10) + jb * 8;
#pragma unroll 4
  for (int r = 0; r < 16; ++r) {
    const unsigned m = bp[(size_t)r << 7];
    const float siv = s_si[(half << 4) + r];
    f16x8 ph;
#pragma unroll
    for (int k = 0; k < 8; ++k) {
      float p;
      if (rd[k] < 0.f)
        p = 0.0009765625f;  // 1/1024 uniform (all-masked column)
      else if ((m >> k) & 1)
        p = __expf(lrelu(siv + sc[k]) - rf[k]) * rd[k];
      else
        p = 0.f;
      ph[k] = (_Float16)p;
    }
    *(f16x8*)(pp + ((size_t)r << 10)) = ph;
  }
}

// ---------------------------------------------------------------------------
extern "C" void kernel_launch(void* const* d_in, const int* in_sizes, int n_in,
                              void* d_out, int out_size, void* d_ws,
                              size_t ws_size, hipStream_t stream) {
  const float* X0 = (const float*)d_in[0];
  const int* mask = (const int*)d_in[1];
  const float* W = (const float*)d_in[2];
  const float* Wb = (const float*)d_in[3];
  const float* A = (const float*)d_in[4];
  const float* Ab = (const float*)d_in[5];
  float* out = (float*)d_out;

  const size_t BSD = (size_t)NBATCH * SS * DF;  // 12,582,912 elems
  const size_t BSS = (size_t)NBATCH * SS * SS;  // 16,777,216 elems
  const size_t BS = (size_t)NBATCH * SS;        // 16,384 elems

  char* p = (char*)d_ws;
  _Float16* X16 = (_Float16*)p;   p += BSD * 2;                   // 24 MB
  _Float16* hT16 = (_Float16*)p;  p += BSD * 2;                   // 24 MB
  _Float16* P16 = (_Float16*)p;   p += BSS * 2;                   // 32 MB
  _Float16* W16 = (_Float16*)p;   p += (size_t)2 * DF * DF * 2;   // 2.25 MB
  unsigned char* bmk = (unsigned char*)p; p += BSS / 8;           // 2 MB
  float* psi2 = (float*)p; p += 2 * BS * 4;   // 128 KB
  float* psj2 = (float*)p; p += 2 * BS * 4;   // 128 KB
  float* pden = (float*)p; p += 64 * BS * 4;  // 4 MB
  float* si = (float*)p;   p += BS * 4;
  float* sjc = (float*)p;  p += BS * 4;
  float* refj = (float*)p; p += BS * 4;
  float* rden = (float*)p; p += BS * 4;

  f32tof16_k<<<12288, 256, 0, stream>>>(X0, X16, (int)BSD);
  f32tof16_k<<<1152, 256, 0, stream>>>(W, W16, 2 * DF * DF);
  pack_k<<<8192, 256, 0, stream>>>(mask, bmk);

  for (int l = 0; l < 2; ++l) {
    gemm1_k<<<256, 512, 0, stream>>>(X16, W16 + (size_t)l * DF * DF,
                                     Wb + (size_t)l * DF,
                                     A + (size_t)l * 2 * DF, hT16, psi2, psj2);
    rowfin_k<<<16, 256, 0, stream>>>(psi2, psj2, Ab + l, si, sjc, refj);
    colsum_k<<<dim3(32, 16), 256, 0, stream>>>(bmk, si, sjc, refj, pden);
    colcomb_k<<<64, 256, 0, stream>>>(pden, rden);
    punorm2_k<<<dim3(32, 16), 256, 0, stream>>>(bmk, si, sjc, refj, rden, P16);
    gemm2_k<<<256, 512, 0, stream>>>(P16, hT16, out + (size_t)l * BSD, X16,
                                     (l == 0) ? 1 : 0);
  }
}